// Round 2
// baseline (671.539 us; speedup 1.0000x reference)
//
#include <hip/hip_runtime.h>
#include <math.h>
#include <stdint.h>

typedef uint32_t u32; typedef uint64_t u64; typedef int32_t i32;

#define BATCH 8
#define NA    261888      // anchors per batch (64 * 4092 exactly)
#define CHUNK 4092
#define TOPK  6000        // PRE_NMS_LIMIT
#define NPAD  6016        // TOPK padded to multiple of 64
#define PROP  1000        // PROPOSAL_COUNT
#define CANDMAX 8192
#define MFAST 1024        // mask-covered prefix of sorted candidates
#define MWORDS 16         // u64 words per mask row (1024 bits)

// ws layout (total 3,022,208 bytes — MUST stay within ws_size; round-1 failure
// was a 6.56 MB layout overrunning d_ws and corrupting the harness's pristine
// input copies: first run exact, every restored run deterministically wrong)
#define OFF_HIST1 0              // 8*4096*4 = 131072
#define OFF_HIST2 131072         // 8*4096*4 = 131072
#define OFF_CNT   262144         // 32
#define OFF_B1G1  262176         // 64
#define OFF_SELP  262240         // 32
#define OFF_KEYS  262272         // 8*8192*8 = 524288
#define OFF_SIDX  786560         // 8*6016*4 = 192512
#define OFF_BOX   979072         // 8*6016*16 = 770048
#define OFF_AREA  1749120        // 8*6016*4 = 192512
#define OFF_SEL   1941632        // 8*1000*4 = 32000
#define OFF_MASK  1973632        // 8*1024*16*8 = 1048576
#define WS_NEEDED 3022208

// ---------------- phase 1: exact top-K select via 2-level bit histogram ----

__global__ void k_hist1(const float* __restrict__ probs, u32* __restrict__ hist1) {
    __shared__ u32 h[4096];
    const int b = blockIdx.y;
    const int base = blockIdx.x * CHUNK;
    for (int i = threadIdx.x; i < 4096; i += 256) h[i] = 0;
    __syncthreads();
    for (int e = threadIdx.x; e < CHUNK; e += 256) {
        int a = base + e;
        u32 bits = __float_as_uint(probs[((size_t)b * NA + a) * 2 + 1]);
        atomicAdd(&h[bits >> 18], 1u);   // scores in [0,1) -> bin < 4064
    }
    __syncthreads();
    for (int i = threadIdx.x; i < 4096; i += 256)
        if (h[i]) atomicAdd(&hist1[b * 4096 + i], h[i]);
}

__global__ void k_select1(const u32* __restrict__ hist1, u32* __restrict__ b1g1) {
    __shared__ u32 ps[256];
    const int b = blockIdx.x;
    const u32* h = hist1 + b * 4096;
    u32 s = 0;
    for (int k = 0; k < 16; ++k) s += h[threadIdx.x * 16 + k];
    ps[threadIdx.x] = s;
    __syncthreads();
    if (threadIdx.x == 0) {
        u32 acc = 0; int seg = 0;
        for (int t = 255; t >= 0; --t) {
            if (acc + ps[t] >= TOPK) { seg = t; break; }
            acc += ps[t];
        }
        int b1 = seg * 16; u32 g1 = acc;
        for (int k = 15; k >= 0; --k) {
            u32 c = h[seg * 16 + k];
            if (g1 + c >= TOPK) { b1 = seg * 16 + k; break; }
            g1 += c;
        }
        b1g1[b * 2] = (u32)b1;   // bin containing rank-TOPK
        b1g1[b * 2 + 1] = g1;    // count strictly above bin b1
    }
}

// level-2: 4096 bins on bits[17:6] within bin b1 (64-ulp granularity;
// expected occupancy of the final bin ~1 -> cnt stays ~TOPK+few)
__global__ void k_hist2(const float* __restrict__ probs, const u32* __restrict__ b1g1,
                        u32* __restrict__ hist2) {
    __shared__ u32 h[4096];
    const int b = blockIdx.y;
    const u32 b1 = b1g1[b * 2];
    const int base = blockIdx.x * CHUNK;
    for (int i = threadIdx.x; i < 4096; i += 256) h[i] = 0;
    __syncthreads();
    for (int e = threadIdx.x; e < CHUNK; e += 256) {
        int a = base + e;
        u32 bits = __float_as_uint(probs[((size_t)b * NA + a) * 2 + 1]);
        if ((bits >> 18) == b1) atomicAdd(&h[(bits >> 6) & 0xFFFu], 1u);
    }
    __syncthreads();
    for (int i = threadIdx.x; i < 4096; i += 256)
        if (h[i]) atomicAdd(&hist2[b * 4096 + i], h[i]);
}

__global__ void k_select2(const u32* __restrict__ hist2, const u32* __restrict__ b1g1,
                          u32* __restrict__ selP) {
    __shared__ u32 ps[256];
    const int b = blockIdx.x;
    const u32* h = hist2 + b * 4096;
    u32 s = 0;
    for (int k = 0; k < 16; ++k) s += h[threadIdx.x * 16 + k];
    ps[threadIdx.x] = s;
    __syncthreads();
    if (threadIdx.x == 0) {
        const u32 b1 = b1g1[b * 2], g1 = b1g1[b * 2 + 1];
        u32 acc = g1; int seg = 0;
        for (int t = 255; t >= 0; --t) {
            if (acc + ps[t] >= TOPK) { seg = t; break; }
            acc += ps[t];
        }
        int b2 = seg * 16; u32 g = acc;
        for (int k = 15; k >= 0; --k) {
            u32 c = h[seg * 16 + k];
            if (g + c >= TOPK) { b2 = seg * 16 + k; break; }
            g += c;
        }
        selP[b] = (b1 << 18) | ((u32)b2 << 6);   // candidates = { bits >= P }, count in [6000, ~6010]
    }
}

__global__ void k_compact(const float* __restrict__ probs, const u32* __restrict__ selP,
                          u32* __restrict__ cnt, u64* __restrict__ keys) {
    const int b = blockIdx.y;
    const u32 P = selP[b];
    const int base = blockIdx.x * CHUNK;
    for (int e = threadIdx.x; e < CHUNK; e += 256) {
        int a = base + e;
        u32 bits = __float_as_uint(probs[((size_t)b * NA + a) * 2 + 1]);
        if (bits >= P) {
            u32 pos = atomicAdd(&cnt[b], 1u);
            if (pos < CANDMAX)
                keys[(size_t)b * CANDMAX + pos] = ((u64)(~bits) << 32) | (u64)(u32)a;
        }
    }
}

// ascending bitonic sort of 8192 u64 keys: (~score_bits, index) == lax.top_k order + tie-break
__global__ __launch_bounds__(1024) void k_sort(const u32* __restrict__ cnt,
                                               const u64* __restrict__ keys,
                                               u32* __restrict__ sortedIdx) {
    __shared__ u64 s[CANDMAX];
    const int b = blockIdx.x;
    u32 n = cnt[b]; if (n > CANDMAX) n = CANDMAX;
    for (int i = threadIdx.x; i < CANDMAX; i += 1024)
        s[i] = (i < (int)n) ? keys[(size_t)b * CANDMAX + i] : ~0ull;
    __syncthreads();
    for (int k = 2; k <= CANDMAX; k <<= 1) {
        for (int j = k >> 1; j > 0; j >>= 1) {
            for (int p = threadIdx.x; p < CANDMAX / 2; p += 1024) {
                int i = ((p & ~(j - 1)) << 1) | (p & (j - 1));
                int l = i | j;
                u64 a = s[i], c = s[l];
                bool up = ((i & k) == 0);
                if ((a > c) == up) { s[i] = c; s[l] = a; }
            }
            __syncthreads();
        }
    }
    for (int i = threadIdx.x; i < NPAD; i += 1024)
        sortedIdx[b * NPAD + i] = (u32)s[i];   // low 32 = anchor index; pad -> 0xFFFFFFFF
}

// ---------------- phase 2: decode boxes (bit-faithful to numpy fp32) -------

__global__ void k_decode(const float4* __restrict__ anchors, const float4* __restrict__ bbox,
                         const u32* __restrict__ sortedIdx, float4* __restrict__ boxes,
                         float* __restrict__ areas) {
    int gid = blockIdx.x * 256 + threadIdx.x;
    if (gid >= BATCH * NPAD) return;
    int b = gid / NPAD;
    u32 idx = sortedIdx[gid];
    float4 bx; float ar;
    if (idx == 0xFFFFFFFFu) {           // pad slot: sentinel far-away box, never suppresses
        bx = make_float4(-5.f, -5.f, -5.f, -5.f); ar = 0.f;
    } else {
        float4 an = anchors[(size_t)b * NA + idx];
        float4 dl = bbox[(size_t)b * NA + idx];
        float d0 = __fmul_rn(dl.x, 0.1f), d1 = __fmul_rn(dl.y, 0.1f);
        float d2 = __fmul_rn(dl.z, 0.2f), d3 = __fmul_rn(dl.w, 0.2f);
        float h = __fsub_rn(an.z, an.x), w = __fsub_rn(an.w, an.y);
        float cy = __fadd_rn(__fadd_rn(an.x, __fmul_rn(0.5f, h)), __fmul_rn(d0, h));
        float cx = __fadd_rn(__fadd_rn(an.y, __fmul_rn(0.5f, w)), __fmul_rn(d1, w));
        float h2 = __fmul_rn(h, (float)exp((double)d2));   // correctly-rounded fp32 exp
        float w2 = __fmul_rn(w, (float)exp((double)d3));
        float y1 = __fsub_rn(cy, __fmul_rn(0.5f, h2));
        float x1 = __fsub_rn(cx, __fmul_rn(0.5f, w2));
        float y2 = __fadd_rn(y1, h2);
        float x2 = __fadd_rn(x1, w2);
        y1 = fminf(fmaxf(y1, 0.f), 1.f); x1 = fminf(fmaxf(x1, 0.f), 1.f);
        y2 = fminf(fmaxf(y2, 0.f), 1.f); x2 = fminf(fmaxf(x2, 0.f), 1.f);
        bx = make_float4(y1, x1, y2, x2);
        ar = __fmul_rn(__fsub_rn(y2, y1), __fsub_rn(x2, x1));
    }
    boxes[gid] = bx;
    areas[gid] = ar;
}

// ---------------- phase 3: NMS ---------------------------------------------
// suppress(i,j)  <=>  RN(inter/union) > 0.7f  <=>  inter >= ((double)0.7f + 2^-25) * union
// (product has <= 49 significant bits -> double compare is EXACT, incl. tie-to-even midpoint)

__global__ void k_mask(const float4* __restrict__ boxes, const float* __restrict__ areas,
                       u64* __restrict__ mask) {
    __shared__ float4 jb[64];
    __shared__ float  ja[64];
    const int b = blockIdx.y;
    const int it = blockIdx.x;                 // MFAST/64 i-tiles of 64 rows
    const int wave = threadIdx.x >> 6, lane = threadIdx.x & 63;
    const double tmid = (double)0.7f + 0x1p-25;
    for (int jt = 0; jt < MFAST / 64; ++jt) {
        __syncthreads();
        if (threadIdx.x < 64) {
            jb[threadIdx.x] = boxes[b * NPAD + jt * 64 + threadIdx.x];
            ja[threadIdx.x] = areas[b * NPAD + jt * 64 + threadIdx.x];
        }
        __syncthreads();
        float4 bj = jb[lane]; float aj = ja[lane];
        for (int r = 0; r < 16; ++r) {
            int i = it * 64 + wave * 16 + r;
            float4 bi = boxes[b * NPAD + i];
            float  ai = areas[b * NPAD + i];
            float yy1 = fmaxf(bi.x, bj.x), xx1 = fmaxf(bi.y, bj.y);
            float yy2 = fminf(bi.z, bj.z), xx2 = fminf(bi.w, bj.w);
            float ih = fmaxf(__fsub_rn(yy2, yy1), 0.f);
            float iw = fmaxf(__fsub_rn(xx2, xx1), 0.f);
            float inter = __fmul_rn(ih, iw);
            float uni = __fsub_rn(__fadd_rn(ai, aj), inter);
            bool sup = (uni > 0.f) && ((double)inter >= tmid * (double)uni);
            u64 word = __ballot(sup);
            if (lane == 0) mask[((size_t)(b * MFAST + i)) * MWORDS + jt] = word;
        }
    }
}

__global__ __launch_bounds__(64) void k_scan(const u64* __restrict__ mask,
                                             const float4* __restrict__ boxes,
                                             const float* __restrict__ areas,
                                             i32* __restrict__ selIdx) {
    __shared__ i32 acc[PROP];
    const int b = blockIdx.x;
    const int lane = threadIdx.x;                       // 0..63
    const int wl = lane & 31;                           // row is 32 u32 words; lanes mirrored
    const u32* mrow = (const u32*)(mask + (size_t)b * MFAST * MWORDS); // 32 u32 per row
    u32 valid = 0xFFFFFFFFu;                            // lane wl owns bits i in [32wl, 32wl+32)
    int cnt = 0;
    u32 pf[16];
    #pragma unroll
    for (int g = 0; g < 16; ++g) pf[g] = mrow[g * 32 + wl];
    for (int base = 0; base < MFAST && cnt < PROP; base += 16) {
        #pragma unroll
        for (int g = 0; g < 16; ++g) {
            if (cnt < PROP) {
                int i = base + g;
                u32 vw = __shfl(valid, i >> 5);         // source lane in [0,32)
                if ((vw >> (i & 31)) & 1u) {
                    if (lane == 0) { selIdx[b * PROP + cnt] = i; acc[cnt] = i; }
                    valid &= ~pf[g];
                    ++cnt;
                }
            }
            int nr = base + g + 16; if (nr > MFAST - 1) nr = MFAST - 1;
            pf[g] = mrow[nr * 32 + wl];                 // 16-deep row prefetch
        }
    }
    // exact fallback beyond MFAST (expected untaken: 1000th accept ~ position 1005)
    const double tmid = (double)0.7f + 0x1p-25;
    for (int i = MFAST; i < TOPK && cnt < PROP; ++i) {
        float4 bi = boxes[b * NPAD + i];
        float  ai = areas[b * NPAD + i];
        bool any = false;
        for (int c = 0; c < cnt; c += 64) {
            bool sup = false;
            int s = c + lane;
            if (s < cnt) {
                int j = acc[s];
                float4 bj = boxes[b * NPAD + j];
                float  aj = areas[b * NPAD + j];
                float yy1 = fmaxf(bi.x, bj.x), xx1 = fmaxf(bi.y, bj.y);
                float yy2 = fminf(bi.z, bj.z), xx2 = fminf(bi.w, bj.w);
                float ih = fmaxf(__fsub_rn(yy2, yy1), 0.f);
                float iw = fmaxf(__fsub_rn(xx2, xx1), 0.f);
                float inter = __fmul_rn(ih, iw);
                float uni = __fsub_rn(__fadd_rn(ai, aj), inter);
                sup = (uni > 0.f) && ((double)inter >= tmid * (double)uni);
            }
            if (__ballot(sup) != 0ull) { any = true; break; }
        }
        if (!any) {
            if (lane == 0) { selIdx[b * PROP + cnt] = i; acc[cnt] = i; }
            ++cnt;
        }
    }
    for (int s2 = cnt + lane; s2 < PROP; s2 += 64) selIdx[b * PROP + s2] = -1;
}

__global__ void k_out(const i32* __restrict__ selIdx, const float4* __restrict__ boxes,
                      float4* __restrict__ out) {
    int t = blockIdx.x * 256 + threadIdx.x;
    if (t >= BATCH * PROP) return;
    int b = t / PROP;
    i32 s = selIdx[t];
    float4 v = make_float4(0.f, 0.f, 0.f, 0.f);
    if (s >= 0) v = boxes[(size_t)b * NPAD + s];
    out[t] = v;
}

// ---------------- launch ----------------------------------------------------

extern "C" void kernel_launch(void* const* d_in, const int* in_sizes, int n_in,
                              void* d_out, int out_size, void* d_ws, size_t ws_size,
                              hipStream_t stream) {
    (void)in_sizes; (void)n_in; (void)out_size;
    if (ws_size < (size_t)WS_NEEDED) return;   // ws_size is constant per process -> same work every call
    const float*  probs   = (const float*)d_in[0];
    const float4* bbox    = (const float4*)d_in[1];
    const float4* anchors = (const float4*)d_in[2];
    float4* out = (float4*)d_out;

    char* ws = (char*)d_ws;
    u32* hist1     = (u32*)(ws + OFF_HIST1);
    u32* hist2     = (u32*)(ws + OFF_HIST2);
    u32* cnt       = (u32*)(ws + OFF_CNT);
    u32* b1g1      = (u32*)(ws + OFF_B1G1);
    u32* selP      = (u32*)(ws + OFF_SELP);
    u64* keys      = (u64*)(ws + OFF_KEYS);
    u32* sortedIdx = (u32*)(ws + OFF_SIDX);
    float4* boxes  = (float4*)(ws + OFF_BOX);
    float* areas   = (float*)(ws + OFF_AREA);
    i32* selIdx    = (i32*)(ws + OFF_SEL);
    u64* mask      = (u64*)(ws + OFF_MASK);

    hipMemsetAsync(ws, 0, OFF_B1G1, stream);     // hist1 + hist2 + cnt

    dim3 g64(64, BATCH);
    k_hist1  <<<g64,   256, 0, stream>>>(probs, hist1);
    k_select1<<<BATCH, 256, 0, stream>>>(hist1, b1g1);
    k_hist2  <<<g64,   256, 0, stream>>>(probs, b1g1, hist2);
    k_select2<<<BATCH, 256, 0, stream>>>(hist2, b1g1, selP);
    k_compact<<<g64,   256, 0, stream>>>(probs, selP, cnt, keys);
    k_sort   <<<BATCH, 1024, 0, stream>>>(cnt, keys, sortedIdx);
    k_decode <<<(BATCH * NPAD) / 256, 256, 0, stream>>>(anchors, bbox, sortedIdx, boxes, areas);
    dim3 gm(MFAST / 64, BATCH);
    k_mask   <<<gm, 256, 0, stream>>>(boxes, areas, mask);
    k_scan   <<<BATCH, 64, 0, stream>>>(mask, boxes, areas, selIdx);
    k_out    <<<(BATCH * PROP + 255) / 256, 256, 0, stream>>>(selIdx, boxes, out);
}

// Round 3
// 408.803 us; speedup vs baseline: 1.6427x; 1.6427x over previous
//
#include <hip/hip_runtime.h>
#include <math.h>
#include <stdint.h>

typedef uint32_t u32; typedef uint64_t u64; typedef uint16_t u16; typedef int32_t i32;

#define BATCH 8
#define NA    261888      // anchors per batch
#define CHUNK 4092        // elements per compact/hist2 block (64 blocks/batch)
#define H1CHUNK 16368     // elements per hist1 block (16 blocks/batch)
#define H1BLK 16
#define TOPK  6000        // PRE_NMS_LIMIT
#define NPAD  6016        // TOPK padded to multiple of 64
#define PROP  1000        // PROPOSAL_COUNT
#define CANDMAX 8192
#define MFAST 1024        // mask-covered prefix of sorted candidates
#define MWORDS 16         // u64 words per mask row (1024 bits)

// ws layout — 2,978,176 B total (< round-2-proven 3,022,208; round-1 lesson:
// never exceed proven ws_size). hist1 partials region is REUSED for boxes+areas
// (phase-1 scratch dead by the time k_decode runs; stream-ordered, safe).
#define OFF_H1P   0              // 8*16*4096*2 = 1,048,576 (u16 partial hists)
#define OFF_BOX   0              // 8*6016*16   =   770,048 (aliased over H1P)
#define OFF_AREA  770048         // 8*6016*4    =   192,512 (aliased over H1P)
#define OFF_HIST2 1048576        // 8*4096*4    =   131,072 (zeroed)
#define OFF_CNT   1179648        // 8*32*4      =     1,024 (zeroed; 128B-padded counters)
#define OFF_B1G1  1180672        // 64
#define OFF_SELP  1180736        // 64
#define OFF_KEYS  1180800        // 8*8192*8    =   524,288
#define OFF_SIDX  1705088        // 8*6016*4    =   192,512
#define OFF_SEL   1897600        // 8*1000*4    =    32,000
#define OFF_MASK  1929600        // 8*1024*16*8 = 1,048,576
#define WS_NEEDED 2978176

// ---------------- phase 1: exact top-K select via 2-level bit histogram ----

// atomic-free: per-block u16 partial histograms, merged in k_select1
__global__ void k_hist1(const float* __restrict__ probs, u16* __restrict__ h1p) {
    __shared__ u32 h[4096];
    const int b = blockIdx.y;
    const int base = blockIdx.x * H1CHUNK;
    for (int i = threadIdx.x; i < 4096; i += 256) h[i] = 0;
    __syncthreads();
    for (int e = threadIdx.x; e < H1CHUNK; e += 256) {
        int a = base + e;
        u32 bits = __float_as_uint(probs[((size_t)b * NA + a) * 2 + 1]);
        atomicAdd(&h[bits >> 18], 1u);   // LDS atomic; scores in [0,1) -> bin < 4064
    }
    __syncthreads();
    u16* dst = h1p + ((size_t)b * H1BLK + blockIdx.x) * 4096;
    for (int i = threadIdx.x; i < 4096; i += 256) dst[i] = (u16)h[i];  // <=16368 fits u16
}

__global__ void k_select1(const u16* __restrict__ h1p, u32* __restrict__ b1g1) {
    __shared__ u32 merged[4096];
    __shared__ u32 ps[256];
    const int b = blockIdx.x;
    const u16* src = h1p + (size_t)b * H1BLK * 4096;
    u32 s = 0;
    for (int k = 0; k < 16; ++k) {
        int bin = threadIdx.x * 16 + k;
        u32 m = 0;
        for (int blk = 0; blk < H1BLK; ++blk) m += src[blk * 4096 + bin];
        merged[bin] = m; s += m;
    }
    ps[threadIdx.x] = s;
    __syncthreads();
    if (threadIdx.x == 0) {
        u32 acc = 0; int seg = 0;
        for (int t = 255; t >= 0; --t) {
            if (acc + ps[t] >= TOPK) { seg = t; break; }
            acc += ps[t];
        }
        int b1 = seg * 16; u32 g1 = acc;
        for (int k = 15; k >= 0; --k) {
            u32 c = merged[seg * 16 + k];
            if (g1 + c >= TOPK) { b1 = seg * 16 + k; break; }
            g1 += c;
        }
        b1g1[b * 2] = (u32)b1;   // bin containing rank-TOPK
        b1g1[b * 2 + 1] = g1;    // count strictly above bin b1
    }
}

// level-2: 4096 bins on bits[17:6] within bin b1; only ~6k elements/batch land
// here -> sparse flush (~50k atomics total, uncontended) is cheap
__global__ void k_hist2(const float* __restrict__ probs, const u32* __restrict__ b1g1,
                        u32* __restrict__ hist2) {
    __shared__ u32 h[4096];
    const int b = blockIdx.y;
    const u32 b1 = b1g1[b * 2];
    const int base = blockIdx.x * CHUNK;
    for (int i = threadIdx.x; i < 4096; i += 256) h[i] = 0;
    __syncthreads();
    for (int e = threadIdx.x; e < CHUNK; e += 256) {
        int a = base + e;
        u32 bits = __float_as_uint(probs[((size_t)b * NA + a) * 2 + 1]);
        if ((bits >> 18) == b1) atomicAdd(&h[(bits >> 6) & 0xFFFu], 1u);
    }
    __syncthreads();
    for (int i = threadIdx.x; i < 4096; i += 256)
        if (h[i]) atomicAdd(&hist2[b * 4096 + i], h[i]);
}

__global__ void k_select2(const u32* __restrict__ hist2, const u32* __restrict__ b1g1,
                          u32* __restrict__ selP) {
    __shared__ u32 ps[256];
    const int b = blockIdx.x;
    const u32* h = hist2 + b * 4096;
    u32 s = 0;
    for (int k = 0; k < 16; ++k) s += h[threadIdx.x * 16 + k];
    ps[threadIdx.x] = s;
    __syncthreads();
    if (threadIdx.x == 0) {
        const u32 b1 = b1g1[b * 2], g1 = b1g1[b * 2 + 1];
        u32 acc = g1; int seg = 0;
        for (int t = 255; t >= 0; --t) {
            if (acc + ps[t] >= TOPK) { seg = t; break; }
            acc += ps[t];
        }
        int b2 = seg * 16; u32 g = acc;
        for (int k = 15; k >= 0; --k) {
            u32 c = h[seg * 16 + k];
            if (g + c >= TOPK) { b2 = seg * 16 + k; break; }
            g += c;
        }
        selP[b] = (b1 << 18) | ((u32)b2 << 6);   // candidates = { bits >= P }
    }
}

// block-aggregated compaction: ONE global atomic per block (was one per
// candidate -> 48k same-line cross-XCD atomics = the round-2 290us stall).
// Order within keys[] is irrelevant: the 64-bit sort restores exact order.
__global__ void k_compact(const float* __restrict__ probs, const u32* __restrict__ selP,
                          u32* __restrict__ cnt, u64* __restrict__ keys) {
    __shared__ u32 wtot[4];
    __shared__ u32 wbase;
    const int b = blockIdx.y;
    const u32 P = selP[b];
    const int base = blockIdx.x * CHUNK;
    const int lane = threadIdx.x & 63, wave = threadIdx.x >> 6;
    u32 vals[16];
    u32 pmask = 0;
    #pragma unroll
    for (int it = 0; it < 16; ++it) {
        int e = it * 256 + threadIdx.x;
        u32 bits = 0;
        if (e < CHUNK) bits = __float_as_uint(probs[((size_t)b * NA + base + e) * 2 + 1]);
        vals[it] = bits;
        if (e < CHUNK && bits >= P) pmask |= (1u << it);
    }
    int c = __popc(pmask);
    int pre = c;                                   // inclusive prefix within wave
    #pragma unroll
    for (int d = 1; d < 64; d <<= 1) {
        int v = __shfl_up(pre, d);
        if (lane >= d) pre += v;
    }
    if (lane == 63) wtot[wave] = (u32)pre;         // wave total
    __syncthreads();
    if (threadIdx.x == 0) {
        u32 run = 0;
        for (int w = 0; w < 4; ++w) { u32 x = wtot[w]; wtot[w] = run; run += x; }
        wbase = atomicAdd(&cnt[b * 32], run);      // padded counter: no line sharing
    }
    __syncthreads();
    u32 pos = wbase + wtot[wave] + (u32)(pre - c);
    #pragma unroll
    for (int it = 0; it < 16; ++it) {
        if ((pmask >> it) & 1u) {
            if (pos < CANDMAX) {
                u32 a = (u32)(base + it * 256 + threadIdx.x);
                keys[(size_t)b * CANDMAX + pos] = ((u64)(~vals[it]) << 32) | (u64)a;
            }
            ++pos;
        }
    }
}

// ascending bitonic sort of 8192 u64 keys: (~score_bits, index) == lax.top_k order + tie-break
__global__ __launch_bounds__(1024) void k_sort(const u32* __restrict__ cnt,
                                               const u64* __restrict__ keys,
                                               u32* __restrict__ sortedIdx) {
    __shared__ u64 s[CANDMAX];
    const int b = blockIdx.x;
    u32 n = cnt[b * 32]; if (n > CANDMAX) n = CANDMAX;
    for (int i = threadIdx.x; i < CANDMAX; i += 1024)
        s[i] = (i < (int)n) ? keys[(size_t)b * CANDMAX + i] : ~0ull;
    __syncthreads();
    for (int k = 2; k <= CANDMAX; k <<= 1) {
        for (int j = k >> 1; j > 0; j >>= 1) {
            for (int p = threadIdx.x; p < CANDMAX / 2; p += 1024) {
                int i = ((p & ~(j - 1)) << 1) | (p & (j - 1));
                int l = i | j;
                u64 a = s[i], c = s[l];
                bool up = ((i & k) == 0);
                if ((a > c) == up) { s[i] = c; s[l] = a; }
            }
            __syncthreads();
        }
    }
    for (int i = threadIdx.x; i < NPAD; i += 1024)
        sortedIdx[b * NPAD + i] = (u32)s[i];   // low 32 = anchor index; pad -> 0xFFFFFFFF
}

// ---------------- phase 2: decode boxes (bit-faithful to numpy fp32) -------

__global__ void k_decode(const float4* __restrict__ anchors, const float4* __restrict__ bbox,
                         const u32* __restrict__ sortedIdx, float4* __restrict__ boxes,
                         float* __restrict__ areas) {
    int gid = blockIdx.x * 256 + threadIdx.x;
    if (gid >= BATCH * NPAD) return;
    int b = gid / NPAD;
    u32 idx = sortedIdx[gid];
    float4 bx; float ar;
    if (idx == 0xFFFFFFFFu) {           // pad slot: sentinel far-away box, never suppresses
        bx = make_float4(-5.f, -5.f, -5.f, -5.f); ar = 0.f;
    } else {
        float4 an = anchors[(size_t)b * NA + idx];
        float4 dl = bbox[(size_t)b * NA + idx];
        float d0 = __fmul_rn(dl.x, 0.1f), d1 = __fmul_rn(dl.y, 0.1f);
        float d2 = __fmul_rn(dl.z, 0.2f), d3 = __fmul_rn(dl.w, 0.2f);
        float h = __fsub_rn(an.z, an.x), w = __fsub_rn(an.w, an.y);
        float cy = __fadd_rn(__fadd_rn(an.x, __fmul_rn(0.5f, h)), __fmul_rn(d0, h));
        float cx = __fadd_rn(__fadd_rn(an.y, __fmul_rn(0.5f, w)), __fmul_rn(d1, w));
        float h2 = __fmul_rn(h, (float)exp((double)d2));   // correctly-rounded fp32 exp
        float w2 = __fmul_rn(w, (float)exp((double)d3));
        float y1 = __fsub_rn(cy, __fmul_rn(0.5f, h2));
        float x1 = __fsub_rn(cx, __fmul_rn(0.5f, w2));
        float y2 = __fadd_rn(y1, h2);
        float x2 = __fadd_rn(x1, w2);
        y1 = fminf(fmaxf(y1, 0.f), 1.f); x1 = fminf(fmaxf(x1, 0.f), 1.f);
        y2 = fminf(fmaxf(y2, 0.f), 1.f); x2 = fminf(fmaxf(x2, 0.f), 1.f);
        bx = make_float4(y1, x1, y2, x2);
        ar = __fmul_rn(__fsub_rn(y2, y1), __fsub_rn(x2, x1));
    }
    boxes[gid] = bx;
    areas[gid] = ar;
}

// ---------------- phase 3: NMS ---------------------------------------------
// suppress(i,j)  <=>  RN(inter/union) > 0.7f  <=>  inter >= ((double)0.7f + 2^-25) * union
// (product has <= 49 significant bits -> double compare is EXACT, incl. tie-to-even midpoint)

__global__ void k_mask(const float4* __restrict__ boxes, const float* __restrict__ areas,
                       u64* __restrict__ mask) {
    __shared__ float4 jb[64];
    __shared__ float  ja[64];
    const int b = blockIdx.y;
    const int it = blockIdx.x;                 // MFAST/64 i-tiles of 64 rows
    const int wave = threadIdx.x >> 6, lane = threadIdx.x & 63;
    const double tmid = (double)0.7f + 0x1p-25;
    for (int jt = 0; jt < MFAST / 64; ++jt) {
        __syncthreads();
        if (threadIdx.x < 64) {
            jb[threadIdx.x] = boxes[b * NPAD + jt * 64 + threadIdx.x];
            ja[threadIdx.x] = areas[b * NPAD + jt * 64 + threadIdx.x];
        }
        __syncthreads();
        float4 bj = jb[lane]; float aj = ja[lane];
        for (int r = 0; r < 16; ++r) {
            int i = it * 64 + wave * 16 + r;
            float4 bi = boxes[b * NPAD + i];
            float  ai = areas[b * NPAD + i];
            float yy1 = fmaxf(bi.x, bj.x), xx1 = fmaxf(bi.y, bj.y);
            float yy2 = fminf(bi.z, bj.z), xx2 = fminf(bi.w, bj.w);
            float ih = fmaxf(__fsub_rn(yy2, yy1), 0.f);
            float iw = fmaxf(__fsub_rn(xx2, xx1), 0.f);
            float inter = __fmul_rn(ih, iw);
            float uni = __fsub_rn(__fadd_rn(ai, aj), inter);
            bool sup = (uni > 0.f) && ((double)inter >= tmid * (double)uni);
            u64 word = __ballot(sup);
            if (lane == 0) mask[((size_t)(b * MFAST + i)) * MWORDS + jt] = word;
        }
    }
}

__global__ __launch_bounds__(64) void k_scan(const u64* __restrict__ mask,
                                             const float4* __restrict__ boxes,
                                             const float* __restrict__ areas,
                                             i32* __restrict__ selIdx) {
    __shared__ i32 acc[PROP];
    const int b = blockIdx.x;
    const int lane = threadIdx.x;                       // 0..63
    const int wl = lane & 31;                           // row is 32 u32 words; lanes mirrored
    const u32* mrow = (const u32*)(mask + (size_t)b * MFAST * MWORDS); // 32 u32 per row
    u32 valid = 0xFFFFFFFFu;                            // lane wl owns bits i in [32wl, 32wl+32)
    int cnt = 0;
    u32 pf[16];
    #pragma unroll
    for (int g = 0; g < 16; ++g) pf[g] = mrow[g * 32 + wl];
    for (int base = 0; base < MFAST && cnt < PROP; base += 16) {
        #pragma unroll
        for (int g = 0; g < 16; ++g) {
            if (cnt < PROP) {
                int i = base + g;
                u32 vw = __shfl(valid, i >> 5);         // source lane in [0,32)
                if ((vw >> (i & 31)) & 1u) {
                    if (lane == 0) { selIdx[b * PROP + cnt] = i; acc[cnt] = i; }
                    valid &= ~pf[g];
                    ++cnt;
                }
            }
            int nr = base + g + 16; if (nr > MFAST - 1) nr = MFAST - 1;
            pf[g] = mrow[nr * 32 + wl];                 // 16-deep row prefetch
        }
    }
    // exact fallback beyond MFAST (expected untaken: 1000th accept ~ position 1005)
    const double tmid = (double)0.7f + 0x1p-25;
    for (int i = MFAST; i < TOPK && cnt < PROP; ++i) {
        float4 bi = boxes[b * NPAD + i];
        float  ai = areas[b * NPAD + i];
        bool any = false;
        for (int c = 0; c < cnt; c += 64) {
            bool sup = false;
            int s = c + lane;
            if (s < cnt) {
                int j = acc[s];
                float4 bj = boxes[b * NPAD + j];
                float  aj = areas[b * NPAD + j];
                float yy1 = fmaxf(bi.x, bj.x), xx1 = fmaxf(bi.y, bj.y);
                float yy2 = fminf(bi.z, bj.z), xx2 = fminf(bi.w, bj.w);
                float ih = fmaxf(__fsub_rn(yy2, yy1), 0.f);
                float iw = fmaxf(__fsub_rn(xx2, xx1), 0.f);
                float inter = __fmul_rn(ih, iw);
                float uni = __fsub_rn(__fadd_rn(ai, aj), inter);
                sup = (uni > 0.f) && ((double)inter >= tmid * (double)uni);
            }
            if (__ballot(sup) != 0ull) { any = true; break; }
        }
        if (!any) {
            if (lane == 0) { selIdx[b * PROP + cnt] = i; acc[cnt] = i; }
            ++cnt;
        }
    }
    for (int s2 = cnt + lane; s2 < PROP; s2 += 64) selIdx[b * PROP + s2] = -1;
}

__global__ void k_out(const i32* __restrict__ selIdx, const float4* __restrict__ boxes,
                      float4* __restrict__ out) {
    int t = blockIdx.x * 256 + threadIdx.x;
    if (t >= BATCH * PROP) return;
    int b = t / PROP;
    i32 s = selIdx[t];
    float4 v = make_float4(0.f, 0.f, 0.f, 0.f);
    if (s >= 0) v = boxes[(size_t)b * NPAD + s];
    out[t] = v;
}

// ---------------- launch ----------------------------------------------------

extern "C" void kernel_launch(void* const* d_in, const int* in_sizes, int n_in,
                              void* d_out, int out_size, void* d_ws, size_t ws_size,
                              hipStream_t stream) {
    (void)in_sizes; (void)n_in; (void)out_size;
    if (ws_size < (size_t)WS_NEEDED) return;   // ws_size constant per process -> same work every call
    const float*  probs   = (const float*)d_in[0];
    const float4* bbox    = (const float4*)d_in[1];
    const float4* anchors = (const float4*)d_in[2];
    float4* out = (float4*)d_out;

    char* ws = (char*)d_ws;
    u16* h1p       = (u16*)(ws + OFF_H1P);
    float4* boxes  = (float4*)(ws + OFF_BOX);    // aliases h1p (phase-1 scratch dead by decode)
    float* areas   = (float*)(ws + OFF_AREA);
    u32* hist2     = (u32*)(ws + OFF_HIST2);
    u32* cnt       = (u32*)(ws + OFF_CNT);
    u32* b1g1      = (u32*)(ws + OFF_B1G1);
    u32* selP      = (u32*)(ws + OFF_SELP);
    u64* keys      = (u64*)(ws + OFF_KEYS);
    u32* sortedIdx = (u32*)(ws + OFF_SIDX);
    i32* selIdx    = (i32*)(ws + OFF_SEL);
    u64* mask      = (u64*)(ws + OFF_MASK);

    hipMemsetAsync(ws + OFF_HIST2, 0, 131072 + 1024, stream);   // hist2 + cnt

    dim3 g16(H1BLK, BATCH), g64(64, BATCH);
    k_hist1  <<<g16,   256, 0, stream>>>(probs, h1p);
    k_select1<<<BATCH, 256, 0, stream>>>(h1p, b1g1);
    k_hist2  <<<g64,   256, 0, stream>>>(probs, b1g1, hist2);
    k_select2<<<BATCH, 256, 0, stream>>>(hist2, b1g1, selP);
    k_compact<<<g64,   256, 0, stream>>>(probs, selP, cnt, keys);
    k_sort   <<<BATCH, 1024, 0, stream>>>(cnt, keys, sortedIdx);
    k_decode <<<(BATCH * NPAD) / 256, 256, 0, stream>>>(anchors, bbox, sortedIdx, boxes, areas);
    dim3 gm(MFAST / 64, BATCH);
    k_mask   <<<gm, 256, 0, stream>>>(boxes, areas, mask);
    k_scan   <<<BATCH, 64, 0, stream>>>(mask, boxes, areas, selIdx);
    k_out    <<<(BATCH * PROP + 255) / 256, 256, 0, stream>>>(selIdx, boxes, out);
}

// Round 4
// 313.258 us; speedup vs baseline: 2.1437x; 1.3050x over previous
//
#include <hip/hip_runtime.h>
#include <math.h>
#include <stdint.h>

typedef uint32_t u32; typedef uint64_t u64; typedef uint16_t u16; typedef int32_t i32;

#define BATCH 8
#define NA    261888      // anchors per batch
#define CHUNK 4092        // elements per compact/hist2 block (64 blocks/batch)
#define H1CHUNK 16368     // elements per hist1 block (16 blocks/batch)
#define H1BLK 16
#define TOPK  6000        // PRE_NMS_LIMIT
#define NPAD  6016        // TOPK padded to multiple of 64
#define PROP  1000        // PROPOSAL_COUNT
#define CANDMAX 8192
#define MFAST 1024        // mask-covered prefix of sorted candidates
#define MW32  32          // u32 words per 1024-bit candidate bitmap

// ws layout — 2,978,240 B total (< round-2-proven 3,022,208). hist1 partials
// region is REUSED for boxes+areas (phase-1 scratch dead by decode; stream-ordered).
#define OFF_H1P   0              // 8*16*4096*2 = 1,048,576 (u16 partial hists)
#define OFF_BOX   0              // 8*6016*16   =   770,048 (aliased over H1P)
#define OFF_AREA  770048         // 8*6016*4    =   192,512 (aliased over H1P)
#define OFF_HIST2 1048576        // 8*4096*4    =   131,072 (zeroed)
#define OFF_CNT   1179648        // 8*32*4      =     1,024 (zeroed; 128B-padded counters)
#define OFF_B1G1  1180672        // 64
#define OFF_SELP  1180736        // 64
#define OFF_KEYS  1180800        // 8*8192*8    =   524,288
#define OFF_SIDX  1705088        // 8*6016*4    =   192,512
#define OFF_SEL   1897600        // 8*1000*4    =    32,000
#define OFF_MASK  1929600        // u32 maskT[8][32][1024] = 1,048,576 (TRANSPOSED: word-major)
#define OFF_FLAGS 2978176        // 8*2 u32 (V, converged)
#define WS_NEEDED 2978240

// ---------------- phase 1: exact top-K select via 2-level bit histogram ----

// atomic-free: per-block u16 partial histograms, merged in k_select1
__global__ void k_hist1(const float2* __restrict__ p2, u16* __restrict__ h1p) {
    __shared__ u32 h[4096];
    const int b = blockIdx.y;
    const int base = blockIdx.x * H1CHUNK;
    for (int i = threadIdx.x; i < 4096; i += 256) h[i] = 0;
    __syncthreads();
    for (int e = threadIdx.x; e < H1CHUNK; e += 256) {
        u32 bits = __float_as_uint(p2[(size_t)b * NA + base + e].y);  // dwordx2 load
        atomicAdd(&h[bits >> 18], 1u);   // LDS atomic; scores in [0,1) -> bin < 4064
    }
    __syncthreads();
    u16* dst = h1p + ((size_t)b * H1BLK + blockIdx.x) * 4096;
    for (int i = threadIdx.x; i < 4096; i += 256) dst[i] = (u16)h[i];  // <=16368 fits u16
}

__global__ void k_select1(const u16* __restrict__ h1p, u32* __restrict__ b1g1) {
    __shared__ u32 merged[4096];
    __shared__ u32 ps[256];
    const int b = blockIdx.x;
    const u16* src = h1p + (size_t)b * H1BLK * 4096;
    u32 s = 0;
    for (int k = 0; k < 16; ++k) {
        int bin = threadIdx.x * 16 + k;
        u32 m = 0;
        for (int blk = 0; blk < H1BLK; ++blk) m += src[blk * 4096 + bin];
        merged[bin] = m; s += m;
    }
    ps[threadIdx.x] = s;
    __syncthreads();
    if (threadIdx.x == 0) {
        u32 acc = 0; int seg = 0;
        for (int t = 255; t >= 0; --t) {
            if (acc + ps[t] >= TOPK) { seg = t; break; }
            acc += ps[t];
        }
        int b1 = seg * 16; u32 g1 = acc;
        for (int k = 15; k >= 0; --k) {
            u32 c = merged[seg * 16 + k];
            if (g1 + c >= TOPK) { b1 = seg * 16 + k; break; }
            g1 += c;
        }
        b1g1[b * 2] = (u32)b1;   // bin containing rank-TOPK
        b1g1[b * 2 + 1] = g1;    // count strictly above bin b1
    }
}

// level-2: 4096 bins on bits[17:6] within bin b1
__global__ void k_hist2(const float2* __restrict__ p2, const u32* __restrict__ b1g1,
                        u32* __restrict__ hist2) {
    __shared__ u32 h[4096];
    const int b = blockIdx.y;
    const u32 b1 = b1g1[b * 2];
    const int base = blockIdx.x * CHUNK;
    for (int i = threadIdx.x; i < 4096; i += 256) h[i] = 0;
    __syncthreads();
    for (int e = threadIdx.x; e < CHUNK; e += 256) {
        u32 bits = __float_as_uint(p2[(size_t)b * NA + base + e].y);
        if ((bits >> 18) == b1) atomicAdd(&h[(bits >> 6) & 0xFFFu], 1u);
    }
    __syncthreads();
    for (int i = threadIdx.x; i < 4096; i += 256)
        if (h[i]) atomicAdd(&hist2[b * 4096 + i], h[i]);
}

__global__ void k_select2(const u32* __restrict__ hist2, const u32* __restrict__ b1g1,
                          u32* __restrict__ selP) {
    __shared__ u32 ps[256];
    const int b = blockIdx.x;
    const u32* h = hist2 + b * 4096;
    u32 s = 0;
    for (int k = 0; k < 16; ++k) s += h[threadIdx.x * 16 + k];
    ps[threadIdx.x] = s;
    __syncthreads();
    if (threadIdx.x == 0) {
        const u32 b1 = b1g1[b * 2], g1 = b1g1[b * 2 + 1];
        u32 acc = g1; int seg = 0;
        for (int t = 255; t >= 0; --t) {
            if (acc + ps[t] >= TOPK) { seg = t; break; }
            acc += ps[t];
        }
        int b2 = seg * 16; u32 g = acc;
        for (int k = 15; k >= 0; --k) {
            u32 c = h[seg * 16 + k];
            if (g + c >= TOPK) { b2 = seg * 16 + k; break; }
            g += c;
        }
        selP[b] = (b1 << 18) | ((u32)b2 << 6);   // candidates = { bits >= P }
    }
}

// block-aggregated compaction: ONE global atomic per block (round-2 lesson:
// per-candidate same-line cross-XCD atomics were 290us). Order irrelevant:
// the 64-bit sort restores exact (score desc, index asc) order.
__global__ void k_compact(const float2* __restrict__ p2, const u32* __restrict__ selP,
                          u32* __restrict__ cnt, u64* __restrict__ keys) {
    __shared__ u32 wtot[4];
    __shared__ u32 wbase;
    const int b = blockIdx.y;
    const u32 P = selP[b];
    const int base = blockIdx.x * CHUNK;
    const int lane = threadIdx.x & 63, wave = threadIdx.x >> 6;
    u32 vals[16];
    u32 pmask = 0;
    #pragma unroll
    for (int it = 0; it < 16; ++it) {
        int e = it * 256 + threadIdx.x;
        u32 bits = 0;
        if (e < CHUNK) bits = __float_as_uint(p2[(size_t)b * NA + base + e].y);
        vals[it] = bits;
        if (e < CHUNK && bits >= P) pmask |= (1u << it);
    }
    int c = __popc(pmask);
    int pre = c;                                   // inclusive prefix within wave
    #pragma unroll
    for (int d = 1; d < 64; d <<= 1) {
        int v = __shfl_up(pre, d);
        if (lane >= d) pre += v;
    }
    if (lane == 63) wtot[wave] = (u32)pre;
    __syncthreads();
    if (threadIdx.x == 0) {
        u32 run = 0;
        for (int w = 0; w < 4; ++w) { u32 x = wtot[w]; wtot[w] = run; run += x; }
        wbase = atomicAdd(&cnt[b * 32], run);      // padded counter: no line sharing
    }
    __syncthreads();
    u32 pos = wbase + wtot[wave] + (u32)(pre - c);
    #pragma unroll
    for (int it = 0; it < 16; ++it) {
        if ((pmask >> it) & 1u) {
            if (pos < CANDMAX) {
                u32 a = (u32)(base + it * 256 + threadIdx.x);
                keys[(size_t)b * CANDMAX + pos] = ((u64)(~vals[it]) << 32) | (u64)a;
            }
            ++pos;
        }
    }
}

// ascending bitonic sort of 8192 u64 keys: (~score_bits, index) == lax.top_k order + tie-break
__global__ __launch_bounds__(1024) void k_sort(const u32* __restrict__ cnt,
                                               const u64* __restrict__ keys,
                                               u32* __restrict__ sortedIdx) {
    __shared__ u64 s[CANDMAX];
    const int b = blockIdx.x;
    u32 n = cnt[b * 32]; if (n > CANDMAX) n = CANDMAX;
    for (int i = threadIdx.x; i < CANDMAX; i += 1024)
        s[i] = (i < (int)n) ? keys[(size_t)b * CANDMAX + i] : ~0ull;
    __syncthreads();
    for (int k = 2; k <= CANDMAX; k <<= 1) {
        for (int j = k >> 1; j > 0; j >>= 1) {
            for (int p = threadIdx.x; p < CANDMAX / 2; p += 1024) {
                int i = ((p & ~(j - 1)) << 1) | (p & (j - 1));
                int l = i | j;
                u64 a = s[i], c = s[l];
                bool up = ((i & k) == 0);
                if ((a > c) == up) { s[i] = c; s[l] = a; }
            }
            __syncthreads();
        }
    }
    for (int i = threadIdx.x; i < NPAD; i += 1024)
        sortedIdx[b * NPAD + i] = (u32)s[i];   // low 32 = anchor index; pad -> 0xFFFFFFFF
}

// ---------------- phase 2: decode boxes (bit-faithful to numpy fp32) -------

__global__ void k_decode(const float4* __restrict__ anchors, const float4* __restrict__ bbox,
                         const u32* __restrict__ sortedIdx, float4* __restrict__ boxes,
                         float* __restrict__ areas) {
    int gid = blockIdx.x * 256 + threadIdx.x;
    if (gid >= BATCH * NPAD) return;
    int b = gid / NPAD;
    u32 idx = sortedIdx[gid];
    float4 bx; float ar;
    if (idx == 0xFFFFFFFFu) {           // pad slot: sentinel far-away box, never suppresses
        bx = make_float4(-5.f, -5.f, -5.f, -5.f); ar = 0.f;
    } else {
        float4 an = anchors[(size_t)b * NA + idx];
        float4 dl = bbox[(size_t)b * NA + idx];
        float d0 = __fmul_rn(dl.x, 0.1f), d1 = __fmul_rn(dl.y, 0.1f);
        float d2 = __fmul_rn(dl.z, 0.2f), d3 = __fmul_rn(dl.w, 0.2f);
        float h = __fsub_rn(an.z, an.x), w = __fsub_rn(an.w, an.y);
        float cy = __fadd_rn(__fadd_rn(an.x, __fmul_rn(0.5f, h)), __fmul_rn(d0, h));
        float cx = __fadd_rn(__fadd_rn(an.y, __fmul_rn(0.5f, w)), __fmul_rn(d1, w));
        float h2 = __fmul_rn(h, (float)exp((double)d2));   // correctly-rounded fp32 exp
        float w2 = __fmul_rn(w, (float)exp((double)d3));
        float y1 = __fsub_rn(cy, __fmul_rn(0.5f, h2));
        float x1 = __fsub_rn(cx, __fmul_rn(0.5f, w2));
        float y2 = __fadd_rn(y1, h2);
        float x2 = __fadd_rn(x1, w2);
        y1 = fminf(fmaxf(y1, 0.f), 1.f); x1 = fminf(fmaxf(x1, 0.f), 1.f);
        y2 = fminf(fmaxf(y2, 0.f), 1.f); x2 = fminf(fmaxf(x2, 0.f), 1.f);
        bx = make_float4(y1, x1, y2, x2);
        ar = __fmul_rn(__fsub_rn(y2, y1), __fsub_rn(x2, x1));
    }
    boxes[gid] = bx;
    areas[gid] = ar;
}

// ---------------- phase 3: NMS ---------------------------------------------
// suppress(i,j)  <=>  RN(inter/union) > 0.7f  <=>  inter >= ((double)0.7f + 2^-25) * union
// (product has <= 49 significant bits -> double compare is EXACT, incl. tie-to-even midpoint)

// mask stored TRANSPOSED: maskT[b][w][i] = word w (candidates 32w..32w+31) of row i
__global__ void k_mask(const float4* __restrict__ boxes, const float* __restrict__ areas,
                       u32* __restrict__ mt_all) {
    __shared__ float4 jb[64];
    __shared__ float  ja[64];
    const int b = blockIdx.y;
    const int it = blockIdx.x;                 // MFAST/64 i-tiles of 64 rows
    const int wave = threadIdx.x >> 6, lane = threadIdx.x & 63;
    const double tmid = (double)0.7f + 0x1p-25;
    u32* mt = mt_all + (size_t)b * MW32 * MFAST;
    for (int jt = 0; jt < MFAST / 64; ++jt) {
        __syncthreads();
        if (threadIdx.x < 64) {
            jb[threadIdx.x] = boxes[b * NPAD + jt * 64 + threadIdx.x];
            ja[threadIdx.x] = areas[b * NPAD + jt * 64 + threadIdx.x];
        }
        __syncthreads();
        float4 bj = jb[lane]; float aj = ja[lane];
        for (int r = 0; r < 16; ++r) {
            int i = it * 64 + wave * 16 + r;
            float4 bi = boxes[b * NPAD + i];
            float  ai = areas[b * NPAD + i];
            float yy1 = fmaxf(bi.x, bj.x), xx1 = fmaxf(bi.y, bj.y);
            float yy2 = fminf(bi.z, bj.z), xx2 = fminf(bi.w, bj.w);
            float ih = fmaxf(__fsub_rn(yy2, yy1), 0.f);
            float iw = fmaxf(__fsub_rn(xx2, xx1), 0.f);
            float inter = __fmul_rn(ih, iw);
            float uni = __fsub_rn(__fadd_rn(ai, aj), inter);
            bool sup = (uni > 0.f) && ((double)inter >= tmid * (double)uni);
            u64 word = __ballot(sup);
            if (lane == 0) {
                mt[(2 * jt) * MFAST + i]     = (u32)word;
                mt[(2 * jt + 1) * MFAST + i] = (u32)(word >> 32);
            }
        }
    }
}

// Jacobi fixed-point NMS: v_i = !exists j<i: v_j & M[j][i]. Well-founded
// recurrence => unique solution; any fixed point of the parallel sweep IS the
// greedy result. Converges in (suppression chain depth)+1 sweeps (~3 here).
__global__ __launch_bounds__(1024) void k_nms(const u32* __restrict__ mt_all,
                                              i32* __restrict__ selIdx,
                                              u32* __restrict__ flags) {
    __shared__ u32 valid[MW32];
    __shared__ u32 wpre[MW32 + 1];
    __shared__ u32 chg;
    const int b = blockIdx.x;
    const int i = threadIdx.x;                 // candidate 0..1023
    const int wv = i >> 6, lane = i & 63;
    const int wi = i >> 5;
    const u32* mt = mt_all + (size_t)b * MW32 * MFAST;
    u32 row[MW32];                             // row i, masked to j<i (coalesced loads)
    #pragma unroll
    for (int w = 0; w < MW32; ++w) row[w] = 0;
    for (int w = 0; w < wi; ++w) row[w] = mt[w * MFAST + i];
    row[wi] = mt[wi * MFAST + i] & ((1u << (i & 31)) - 1u);   // shift 0 -> 0 mask (kills diag too)
    if (i < MW32) valid[i] = 0xFFFFFFFFu;
    bool conv = false;
    for (int it = 0; it < 48; ++it) {
        __syncthreads();                       // valid init / prev writes visible
        if (i == 0) chg = 0;
        u32 sup = 0;
        #pragma unroll
        for (int w = 0; w < MW32; ++w) sup |= valid[w] & row[w];
        u64 nb = __ballot(sup == 0u);
        __syncthreads();                       // all reads done; chg=0 visible
        if (lane == 0) {
            u32 lo = (u32)nb, hi = (u32)(nb >> 32);
            if (valid[2 * wv] != lo)     { valid[2 * wv] = lo;     atomicOr(&chg, 1u); }
            if (valid[2 * wv + 1] != hi) { valid[2 * wv + 1] = hi; atomicOr(&chg, 1u); }
        }
        __syncthreads();
        if (chg == 0u) { conv = true; break; } // uniform
    }
    __syncthreads();
    if (i == 0) {
        u32 r = 0;
        for (int w = 0; w < MW32; ++w) { wpre[w] = r; r += __popc(valid[w]); }
        wpre[MW32] = r;
        flags[b * 2] = r;                      // V = valid count among first 1024
        flags[b * 2 + 1] = conv ? 1u : 0u;
    }
    __syncthreads();
    u32 vw = valid[wi];
    bool isv = ((vw >> (i & 31)) & 1u) != 0;
    u32 rank = wpre[wi] + __popc(vw & ((1u << (i & 31)) - 1u));
    if (isv && rank < PROP) selIdx[b * PROP + rank] = (i32)i;
    int V = (int)wpre[MW32];
    int start = V < PROP ? V : PROP;
    for (int t = start + i; t < PROP; t += 1024) selIdx[b * PROP + t] = -1;
}

// exact fallback: early-exits when Jacobi converged with >=PROP accepts (the
// expected path). Otherwise runs the exact sequential scan and/or the
// beyond-MFAST tail. Data-dependent branch, deterministic per input.
__global__ __launch_bounds__(64) void k_scan_fb(const u32* __restrict__ mt_all,
                                                const float4* __restrict__ boxes,
                                                const float* __restrict__ areas,
                                                const u32* __restrict__ flags,
                                                i32* __restrict__ selIdx) {
    __shared__ i32 acc[PROP];
    const int b = blockIdx.x;
    const int lane = threadIdx.x;                       // 0..63
    u32 V = flags[b * 2], conv = flags[b * 2 + 1];
    if (conv && V >= PROP) return;                      // fast path: nothing to do
    const u32* mt = mt_all + (size_t)b * MW32 * MFAST;
    const double tmid = (double)0.7f + 0x1p-25;
    int cnt = 0;
    if (conv) {
        cnt = (int)V;                                   // trust Jacobi result, tail only
        for (int s = lane; s < cnt; s += 64) acc[s] = selIdx[b * PROP + s];
        __syncthreads();
    } else {
        const int wl = lane & 31;                       // lane wl owns word wl
        u32 valid = 0xFFFFFFFFu;
        u32 pf[16];
        #pragma unroll
        for (int g = 0; g < 16; ++g) pf[g] = mt[wl * MFAST + g];
        for (int base = 0; base < MFAST && cnt < PROP; base += 16) {
            #pragma unroll
            for (int g = 0; g < 16; ++g) {
                if (cnt < PROP) {
                    int i = base + g;
                    u32 vw = __shfl(valid, i >> 5);
                    if ((vw >> (i & 31)) & 1u) {
                        if (lane == 0) { selIdx[b * PROP + cnt] = i; acc[cnt] = i; }
                        valid &= ~pf[g];
                        ++cnt;
                    }
                }
                int nr = base + g + 16; if (nr > MFAST - 1) nr = MFAST - 1;
                pf[g] = mt[wl * MFAST + nr];
            }
        }
    }
    // exact tail beyond MFAST (expected untaken)
    for (int i = MFAST; i < TOPK && cnt < PROP; ++i) {
        float4 bi = boxes[b * NPAD + i];
        float  ai = areas[b * NPAD + i];
        bool any = false;
        for (int c = 0; c < cnt; c += 64) {
            bool sup = false;
            int s = c + lane;
            if (s < cnt) {
                int j = acc[s];
                float4 bj = boxes[b * NPAD + j];
                float  aj = areas[b * NPAD + j];
                float yy1 = fmaxf(bi.x, bj.x), xx1 = fmaxf(bi.y, bj.y);
                float yy2 = fminf(bi.z, bj.z), xx2 = fminf(bi.w, bj.w);
                float ih = fmaxf(__fsub_rn(yy2, yy1), 0.f);
                float iw = fmaxf(__fsub_rn(xx2, xx1), 0.f);
                float inter = __fmul_rn(ih, iw);
                float uni = __fsub_rn(__fadd_rn(ai, aj), inter);
                sup = (uni > 0.f) && ((double)inter >= tmid * (double)uni);
            }
            if (__ballot(sup) != 0ull) { any = true; break; }
        }
        if (!any) {
            if (lane == 0) { selIdx[b * PROP + cnt] = i; acc[cnt] = i; }
            ++cnt;
        }
    }
    for (int s2 = cnt + lane; s2 < PROP; s2 += 64) selIdx[b * PROP + s2] = -1;
}

__global__ void k_out(const i32* __restrict__ selIdx, const float4* __restrict__ boxes,
                      float4* __restrict__ out) {
    int t = blockIdx.x * 256 + threadIdx.x;
    if (t >= BATCH * PROP) return;
    int b = t / PROP;
    i32 s = selIdx[t];
    float4 v = make_float4(0.f, 0.f, 0.f, 0.f);
    if (s >= 0) v = boxes[(size_t)b * NPAD + s];
    out[t] = v;
}

// ---------------- launch ----------------------------------------------------

extern "C" void kernel_launch(void* const* d_in, const int* in_sizes, int n_in,
                              void* d_out, int out_size, void* d_ws, size_t ws_size,
                              hipStream_t stream) {
    (void)in_sizes; (void)n_in; (void)out_size;
    if (ws_size < (size_t)WS_NEEDED) return;   // ws_size constant per process -> same work every call
    const float2* p2      = (const float2*)d_in[0];
    const float4* bbox    = (const float4*)d_in[1];
    const float4* anchors = (const float4*)d_in[2];
    float4* out = (float4*)d_out;

    char* ws = (char*)d_ws;
    u16* h1p       = (u16*)(ws + OFF_H1P);
    float4* boxes  = (float4*)(ws + OFF_BOX);    // aliases h1p (phase-1 scratch dead by decode)
    float* areas   = (float*)(ws + OFF_AREA);
    u32* hist2     = (u32*)(ws + OFF_HIST2);
    u32* cnt       = (u32*)(ws + OFF_CNT);
    u32* b1g1      = (u32*)(ws + OFF_B1G1);
    u32* selP      = (u32*)(ws + OFF_SELP);
    u64* keys      = (u64*)(ws + OFF_KEYS);
    u32* sortedIdx = (u32*)(ws + OFF_SIDX);
    i32* selIdx    = (i32*)(ws + OFF_SEL);
    u32* maskT     = (u32*)(ws + OFF_MASK);
    u32* flags     = (u32*)(ws + OFF_FLAGS);

    hipMemsetAsync(ws + OFF_HIST2, 0, 131072 + 1024, stream);   // hist2 + cnt

    dim3 g16(H1BLK, BATCH), g64(64, BATCH);
    k_hist1  <<<g16,   256, 0, stream>>>(p2, h1p);
    k_select1<<<BATCH, 256, 0, stream>>>(h1p, b1g1);
    k_hist2  <<<g64,   256, 0, stream>>>(p2, b1g1, hist2);
    k_select2<<<BATCH, 256, 0, stream>>>(hist2, b1g1, selP);
    k_compact<<<g64,   256, 0, stream>>>(p2, selP, cnt, keys);
    k_sort   <<<BATCH, 1024, 0, stream>>>(cnt, keys, sortedIdx);
    k_decode <<<(BATCH * NPAD) / 256, 256, 0, stream>>>(anchors, bbox, sortedIdx, boxes, areas);
    dim3 gm(MFAST / 64, BATCH);
    k_mask   <<<gm, 256, 0, stream>>>(boxes, areas, maskT);
    k_nms    <<<BATCH, 1024, 0, stream>>>(maskT, selIdx, flags);
    k_scan_fb<<<BATCH, 64, 0, stream>>>(maskT, boxes, areas, flags, selIdx);
    k_out    <<<(BATCH * PROP + 255) / 256, 256, 0, stream>>>(selIdx, boxes, out);
}

// Round 5
// 248.673 us; speedup vs baseline: 2.7005x; 1.2597x over previous
//
#include <hip/hip_runtime.h>
#include <math.h>
#include <stdint.h>

typedef uint32_t u32; typedef uint64_t u64; typedef uint16_t u16; typedef int32_t i32;

#define BATCH 8
#define NA    261888      // anchors per batch
#define CHUNK 4092        // elements per hist2cache block (64 blocks/batch)
#define H1CHUNK 16368     // elements per hist1 block (16 blocks/batch)
#define H1BLK 16
#define TOPK  6000        // PRE_NMS_LIMIT (fallback only)
#define PROP  1000        // PROPOSAL_COUNT
#define TOP1  1024        // fast-path window = Jacobi/mask width
#define SORTN 2048        // bitonic size for top-1024 refinement
#define CACHEMAX 8192     // cached candidates >= coarse rank-1024 threshold (~5.1K expected)
#define FBMAX 16384       // fallback candidate capacity (~10.1K expected)
#define MW32  32          // u32 words per 1024-bit candidate bitmap

// ws layout — 2,917,632 B total (< round-4-proven 2,978,240; round-1 lesson:
// never exceed proven ws_size). fbkeys aliases h1p (dead by fb time).
#define OFF_H1P   0              // u16 h1p[8][16][4096]  = 1,048,576
#define OFF_FBK   0              // u64 fbkeys[8][16384]  = 1,048,576 (alias, fb only)
#define OFF_CACHE 1048576        // u64 cache[8][8192]    =   524,288
#define OFF_HIST2 1572864        // u32 hist2[8][4096]    =   131,072 (zeroed)
#define OFF_CNT   1703936        // u32 cnt[8*32]         =     1,024 (zeroed; 128B-padded)
#define OFF_B1G1  1704960        // u32 [8][4]            =       128
#define OFF_SELP  1705088        // u32 [8] (+pad)        =        64
#define OFF_BOX   1705152        // float4 boxes[8][1024] =   131,072
#define OFF_AREA  1836224        // float areas[8][1024]  =    32,768
#define OFF_MASK  1868992        // u32 maskT[8][32][1024]= 1,048,576
#define OFF_FLAGS 2917568        // u32 [8][2] (V, conv)  =        64
#define WS_NEEDED 2917632

// ---------------- shared exact numerics -------------------------------------

// bit-faithful numpy fp32 decode (no FMA contraction; correctly-rounded exp)
__device__ __forceinline__ void decode_box(const float4 an, const float4 dl,
                                           float4& bx, float& ar) {
    float d0 = __fmul_rn(dl.x, 0.1f), d1 = __fmul_rn(dl.y, 0.1f);
    float d2 = __fmul_rn(dl.z, 0.2f), d3 = __fmul_rn(dl.w, 0.2f);
    float h = __fsub_rn(an.z, an.x), w = __fsub_rn(an.w, an.y);
    float cy = __fadd_rn(__fadd_rn(an.x, __fmul_rn(0.5f, h)), __fmul_rn(d0, h));
    float cx = __fadd_rn(__fadd_rn(an.y, __fmul_rn(0.5f, w)), __fmul_rn(d1, w));
    float h2 = __fmul_rn(h, (float)exp((double)d2));
    float w2 = __fmul_rn(w, (float)exp((double)d3));
    float y1 = __fsub_rn(cy, __fmul_rn(0.5f, h2));
    float x1 = __fsub_rn(cx, __fmul_rn(0.5f, w2));
    float y2 = __fadd_rn(y1, h2);
    float x2 = __fadd_rn(x1, w2);
    y1 = fminf(fmaxf(y1, 0.f), 1.f); x1 = fminf(fmaxf(x1, 0.f), 1.f);
    y2 = fminf(fmaxf(y2, 0.f), 1.f); x2 = fminf(fmaxf(x2, 0.f), 1.f);
    bx = make_float4(y1, x1, y2, x2);
    ar = __fmul_rn(__fsub_rn(y2, y1), __fsub_rn(x2, x1));
}

// suppress(i,j) <=> RN(inter/union) > 0.7f <=> inter >= ((double)0.7f+2^-25)*union
// (product <= 49 significant bits -> double compare EXACT incl. tie-to-even midpoint)
__device__ __forceinline__ bool sup_pred(const float4 bi, const float ai,
                                         const float4 bj, const float aj) {
    const double tmid = (double)0.7f + 0x1p-25;
    float yy1 = fmaxf(bi.x, bj.x), xx1 = fmaxf(bi.y, bj.y);
    float yy2 = fminf(bi.z, bj.z), xx2 = fminf(bi.w, bj.w);
    float ih = fmaxf(__fsub_rn(yy2, yy1), 0.f);
    float iw = fmaxf(__fsub_rn(xx2, xx1), 0.f);
    float inter = __fmul_rn(ih, iw);
    float uni = __fsub_rn(__fadd_rn(ai, aj), inter);
    return (uni > 0.f) && ((double)inter >= tmid * (double)uni);
}

// ---------------- phase 1: exact top-1024 select -----------------------------

// atomic-free: per-block u16 partial histograms on bits[31:18]
__global__ void k_hist1(const float2* __restrict__ p2, u16* __restrict__ h1p) {
    __shared__ u32 h[4096];
    const int b = blockIdx.y;
    const int base = blockIdx.x * H1CHUNK;
    for (int i = threadIdx.x; i < 4096; i += 256) h[i] = 0;
    __syncthreads();
    for (int e = threadIdx.x; e < H1CHUNK; e += 256) {
        u32 bits = __float_as_uint(p2[(size_t)b * NA + base + e].y);
        atomicAdd(&h[bits >> 18], 1u);   // LDS atomic; scores in [0,1)
    }
    __syncthreads();
    u16* dst = h1p + ((size_t)b * H1BLK + blockIdx.x) * 4096;
    for (int i = threadIdx.x; i < 4096; i += 256) dst[i] = (u16)h[i];
}

// merge partials; pick coarse bins for rank-1024 (fast path) and rank-6000 (fb)
__global__ void k_select1(const u16* __restrict__ h1p, u32* __restrict__ b1g1) {
    __shared__ u32 merged[4096];
    __shared__ u32 ps[256];
    const int b = blockIdx.x;
    const u16* src = h1p + (size_t)b * H1BLK * 4096;
    u32 s = 0;
    for (int k = 0; k < 16; ++k) {
        int bin = threadIdx.x * 16 + k;
        u32 m = 0;
        for (int blk = 0; blk < H1BLK; ++blk) m += src[blk * 4096 + bin];
        merged[bin] = m; s += m;
    }
    ps[threadIdx.x] = s;
    __syncthreads();
    if (threadIdx.x == 0) {
        {   // rank TOP1
            u32 acc = 0; int seg = 0;
            for (int t = 255; t >= 0; --t) { if (acc + ps[t] >= TOP1) { seg = t; break; } acc += ps[t]; }
            int b1 = seg * 16; u32 g1 = acc;
            for (int k = 15; k >= 0; --k) {
                u32 c = merged[seg * 16 + k];
                if (g1 + c >= TOP1) { b1 = seg * 16 + k; break; }
                g1 += c;
            }
            b1g1[b * 4] = (u32)b1; b1g1[b * 4 + 1] = g1;
        }
        {   // rank TOPK (fallback threshold only)
            u32 acc = 0; int seg = 0;
            for (int t = 255; t >= 0; --t) { if (acc + ps[t] >= TOPK) { seg = t; break; } acc += ps[t]; }
            int b6 = seg * 16; u32 g6 = acc;
            for (int k = 15; k >= 0; --k) {
                u32 c = merged[seg * 16 + k];
                if (g6 + c >= TOPK) { b6 = seg * 16 + k; break; }
                g6 += c;
            }
            b1g1[b * 4 + 2] = (u32)b6;
        }
    }
}

// fused: refine-histogram bin b1 on bits[17:6] AND cache all candidates with
// bits >= (b1<<18) (~5.1K/batch) via block-aggregated allocation (1 atomic/block)
__global__ void k_hist2cache(const float2* __restrict__ p2, const u32* __restrict__ b1g1,
                             u32* __restrict__ hist2, u32* __restrict__ cnt,
                             u64* __restrict__ cache) {
    __shared__ u32 h[4096];
    __shared__ u32 wtot[4];
    __shared__ u32 wbase;
    const int b = blockIdx.y;
    const u32 b1 = b1g1[b * 4];
    const u32 Pc = b1 << 18;
    const int base = blockIdx.x * CHUNK;
    const int lane = threadIdx.x & 63, wave = threadIdx.x >> 6;
    for (int i = threadIdx.x; i < 4096; i += 256) h[i] = 0;
    __syncthreads();
    u32 vals[16];
    u32 pmask = 0;
    #pragma unroll
    for (int it = 0; it < 16; ++it) {
        int e = it * 256 + threadIdx.x;
        u32 bits = 0;
        if (e < CHUNK) bits = __float_as_uint(p2[(size_t)b * NA + base + e].y);
        vals[it] = bits;
        if (e < CHUNK && bits >= Pc) {
            pmask |= (1u << it);
            if ((bits >> 18) == b1) atomicAdd(&h[(bits >> 6) & 0xFFFu], 1u);
        }
    }
    int c = __popc(pmask);
    int pre = c;                                   // inclusive prefix within wave
    #pragma unroll
    for (int d = 1; d < 64; d <<= 1) {
        int v = __shfl_up(pre, d);
        if (lane >= d) pre += v;
    }
    if (lane == 63) wtot[wave] = (u32)pre;
    __syncthreads();
    if (threadIdx.x == 0) {
        u32 run = 0;
        for (int w = 0; w < 4; ++w) { u32 x = wtot[w]; wtot[w] = run; run += x; }
        wbase = atomicAdd(&cnt[b * 32], run);      // padded counter: no line sharing
    }
    __syncthreads();
    u32 pos = wbase + wtot[wave] + (u32)(pre - c);
    #pragma unroll
    for (int it = 0; it < 16; ++it) {
        if ((pmask >> it) & 1u) {
            if (pos < CACHEMAX) {
                u32 a = (u32)(base + it * 256 + threadIdx.x);
                cache[(size_t)b * CACHEMAX + pos] = ((u64)(~vals[it]) << 32) | (u64)a;
            }
            ++pos;
        }
    }
    // sparse flush (~64 nonzero bins/block)
    for (int i = threadIdx.x; i < 4096; i += 256)
        if (h[i]) atomicAdd(&hist2[b * 4096 + i], h[i]);
}

__global__ void k_select2(const u32* __restrict__ hist2, const u32* __restrict__ b1g1,
                          u32* __restrict__ selP) {
    __shared__ u32 ps[256];
    const int b = blockIdx.x;
    const u32* h = hist2 + b * 4096;
    u32 s = 0;
    for (int k = 0; k < 16; ++k) s += h[threadIdx.x * 16 + k];
    ps[threadIdx.x] = s;
    __syncthreads();
    if (threadIdx.x == 0) {
        const u32 b1 = b1g1[b * 4], g1 = b1g1[b * 4 + 1];
        u32 acc = g1; int seg = 0;
        for (int t = 255; t >= 0; --t) {
            if (acc + ps[t] >= TOP1) { seg = t; break; }
            acc += ps[t];
        }
        int b2 = seg * 16; u32 g = acc;
        for (int k = 15; k >= 0; --k) {
            u32 c = h[seg * 16 + k];
            if (g + c >= TOP1) { b2 = seg * 16 + k; break; }
            g += c;
        }
        selP[b] = (b1 << 18) | ((u32)b2 << 6);   // count(bits>=P) in [1024, ~1030]
    }
}

// filter cache by refined P, bitonic-sort 2048 in LDS (exact lax.top_k order:
// key = (~score_bits, index)), then decode the top-1024 in the same kernel
__global__ __launch_bounds__(1024) void k_sortdec(const u32* __restrict__ cnt,
                                                  const u64* __restrict__ cache,
                                                  const u32* __restrict__ selP,
                                                  const float4* __restrict__ anchors,
                                                  const float4* __restrict__ bbox,
                                                  float4* __restrict__ boxes,
                                                  float* __restrict__ areas) {
    __shared__ u64 s[SORTN];
    __shared__ u32 m;
    const int b = blockIdx.x;
    const u32 P = selP[b];
    const u64 thrKey = ((u64)(~P) << 32) | 0xFFFFFFFFull;   // key<=thrKey <=> bits>=P
    u32 nc = cnt[b * 32]; if (nc > CACHEMAX) nc = CACHEMAX;
    if (threadIdx.x == 0) m = 0;
    for (int i = threadIdx.x; i < SORTN; i += 1024) s[i] = ~0ull;
    __syncthreads();
    for (int t = threadIdx.x; t < (int)nc; t += 1024) {
        u64 key = cache[(size_t)b * CACHEMAX + t];
        if (key <= thrKey) {
            u32 slot = atomicAdd(&m, 1u);
            if (slot < SORTN) s[slot] = key;     // overflow impossible; fb guards anyway
        }
    }
    __syncthreads();
    for (int k = 2; k <= SORTN; k <<= 1) {
        for (int j = k >> 1; j > 0; j >>= 1) {
            int p = threadIdx.x;                 // exactly SORTN/2 pairs
            int i = ((p & ~(j - 1)) << 1) | (p & (j - 1));
            int l = i | j;
            u64 a = s[i], c = s[l];
            bool up = ((i & k) == 0);
            if ((a > c) == up) { s[i] = c; s[l] = a; }
            __syncthreads();
        }
    }
    int i = threadIdx.x;                          // 0..1023: decode sorted top-1024
    u32 idx = (u32)s[i];
    float4 bx; float ar;
    if (idx == 0xFFFFFFFFu) {                     // unreachable (n1>=1024); OOB guard
        bx = make_float4(-5.f, -5.f, -5.f, -5.f); ar = 0.f;
    } else {
        decode_box(anchors[(size_t)b * NA + idx], bbox[(size_t)b * NA + idx], bx, ar);
    }
    boxes[b * TOP1 + i] = bx;
    areas[b * TOP1 + i] = ar;
}

// ---------------- phase 3: NMS ----------------------------------------------

// mask stored TRANSPOSED: maskT[b][w][i] = word w (candidates 32w..32w+31) of row i
__global__ void k_mask(const float4* __restrict__ boxes, const float* __restrict__ areas,
                       u32* __restrict__ mt_all) {
    __shared__ float4 jb[64];
    __shared__ float  ja[64];
    const int b = blockIdx.y;
    const int it = blockIdx.x;                 // 16 i-tiles of 64 rows
    const int wave = threadIdx.x >> 6, lane = threadIdx.x & 63;
    u32* mt = mt_all + (size_t)b * MW32 * TOP1;
    for (int jt = 0; jt < TOP1 / 64; ++jt) {
        __syncthreads();
        if (threadIdx.x < 64) {
            jb[threadIdx.x] = boxes[b * TOP1 + jt * 64 + threadIdx.x];
            ja[threadIdx.x] = areas[b * TOP1 + jt * 64 + threadIdx.x];
        }
        __syncthreads();
        float4 bj = jb[lane]; float aj = ja[lane];
        for (int r = 0; r < 16; ++r) {
            int i = it * 64 + wave * 16 + r;
            float4 bi = boxes[b * TOP1 + i];
            float  ai = areas[b * TOP1 + i];
            u64 word = __ballot(sup_pred(bi, ai, bj, aj));
            if (lane == 0) {
                mt[(2 * jt) * TOP1 + i]     = (u32)word;
                mt[(2 * jt + 1) * TOP1 + i] = (u32)(word >> 32);
            }
        }
    }
}

// Jacobi fixed-point NMS (unique fixed point == greedy result); writes d_out
__global__ __launch_bounds__(1024) void k_nms(const u32* __restrict__ mt_all,
                                              const float4* __restrict__ boxes,
                                              float4* __restrict__ out,
                                              u32* __restrict__ flags) {
    __shared__ u32 valid[MW32];
    __shared__ u32 wpre[MW32 + 1];
    __shared__ u32 chg;
    const int b = blockIdx.x;
    const int i = threadIdx.x;                 // candidate 0..1023
    const int wv = i >> 6, lane = i & 63;
    const int wi = i >> 5;
    const u32* mt = mt_all + (size_t)b * MW32 * TOP1;
    u32 row[MW32];                             // row i, masked to j<i (coalesced loads)
    #pragma unroll
    for (int w = 0; w < MW32; ++w) row[w] = 0;
    for (int w = 0; w < wi; ++w) row[w] = mt[w * TOP1 + i];
    row[wi] = mt[wi * TOP1 + i] & ((1u << (i & 31)) - 1u);
    if (i < MW32) valid[i] = 0xFFFFFFFFu;
    bool conv = false;
    for (int it = 0; it < 48; ++it) {
        __syncthreads();
        if (i == 0) chg = 0;
        u32 sup = 0;
        #pragma unroll
        for (int w = 0; w < MW32; ++w) sup |= valid[w] & row[w];
        u64 nb = __ballot(sup == 0u);
        __syncthreads();
        if (lane == 0) {
            u32 lo = (u32)nb, hi = (u32)(nb >> 32);
            if (valid[2 * wv] != lo)     { valid[2 * wv] = lo;     atomicOr(&chg, 1u); }
            if (valid[2 * wv + 1] != hi) { valid[2 * wv + 1] = hi; atomicOr(&chg, 1u); }
        }
        __syncthreads();
        if (chg == 0u) { conv = true; break; }
    }
    __syncthreads();
    if (i == 0) {
        u32 r = 0;
        for (int w = 0; w < MW32; ++w) { wpre[w] = r; r += __popc(valid[w]); }
        wpre[MW32] = r;
        flags[b * 2] = r;
        flags[b * 2 + 1] = conv ? 1u : 0u;
    }
    __syncthreads();
    u32 vw = valid[wi];
    bool isv = ((vw >> (i & 31)) & 1u) != 0;
    u32 rank = wpre[wi] + __popc(vw & ((1u << (i & 31)) - 1u));
    if (isv && rank < PROP) out[b * PROP + rank] = boxes[b * TOP1 + i];
    int V = (int)wpre[MW32];
    int start = V < PROP ? V : PROP;
    for (int t = start + i; t < PROP; t += 1024)
        out[b * PROP + t] = make_float4(0.f, 0.f, 0.f, 0.f);
}

// self-contained EXACT fallback. Fast path (expected always): converged Jacobi
// with >=PROP accepts and no cache overflow -> return. Otherwise redo the
// whole reference computation exactly (slow, never taken; deterministic).
__global__ __launch_bounds__(1024) void k_fb(const float2* __restrict__ p2,
                                             const float4* __restrict__ bbox,
                                             const float4* __restrict__ anchors,
                                             const u32* __restrict__ b1g1,
                                             const u32* __restrict__ cnt,
                                             const u32* __restrict__ flags,
                                             u64* __restrict__ fbkeys,
                                             float4* __restrict__ out) {
    const int b = blockIdx.x;
    u32 V = flags[b * 2], conv = flags[b * 2 + 1];
    u32 cc = cnt[b * 32];
    if (conv && V >= PROP && cc <= CACHEMAX) return;

    const int tid = threadIdx.x;
    __shared__ u32 nsh;
    __shared__ float4 abox[PROP];
    __shared__ float  aar[PROP];
    if (tid == 0) nsh = 0;
    __syncthreads();
    u32 P6 = b1g1[b * 4 + 2] << 18;            // coarse rank-6000 threshold
    for (int a = tid; a < NA; a += 1024) {
        u32 bits = __float_as_uint(p2[(size_t)b * NA + a].y);
        if (bits >= P6) {
            u32 p = atomicAdd(&nsh, 1u);
            if (p < FBMAX) fbkeys[(size_t)b * FBMAX + p] = ((u64)(~bits) << 32) | (u64)a;
        }
    }
    __syncthreads();
    u32 n = nsh; if (n > FBMAX) n = FBMAX;     // ~10.1K expected; overflow impossible
    volatile u64* vk = (volatile u64*)(fbkeys + (size_t)b * FBMAX);
    for (int i2 = (int)n + tid; i2 < FBMAX; i2 += 1024) vk[i2] = ~0ull;
    __syncthreads();
    for (int k = 2; k <= FBMAX; k <<= 1) {     // global-memory bitonic, exact order
        for (int j = k >> 1; j > 0; j >>= 1) {
            for (int p = tid; p < FBMAX / 2; p += 1024) {
                int i = ((p & ~(j - 1)) << 1) | (p & (j - 1));
                int l = i | j;
                u64 a = vk[i], c = vk[l];
                bool up = ((i & k) == 0);
                if ((a > c) == up) { vk[i] = c; vk[l] = a; }
            }
            __syncthreads();
        }
    }
    // sequential exact greedy NMS over sorted top-6000, on-the-fly decode
    int acc_n = 0;
    int limit = (int)n < TOPK ? (int)n : TOPK;
    for (int i = 0; i < limit && acc_n < PROP; ++i) {
        u32 idx = (u32)vk[i];
        float4 bi; float ai;
        decode_box(anchors[(size_t)b * NA + idx], bbox[(size_t)b * NA + idx], bi, ai);
        int pred = 0;
        if (tid < acc_n) pred = sup_pred(bi, ai, abox[tid], aar[tid]) ? 1 : 0;
        int any = __syncthreads_or(pred);
        if (!any) {
            if (tid == 0) {
                abox[acc_n] = bi; aar[acc_n] = ai;
                out[b * PROP + acc_n] = bi;
            }
            ++acc_n;
            __syncthreads();
        }
    }
    for (int t = acc_n + tid; t < PROP; t += 1024)
        out[b * PROP + t] = make_float4(0.f, 0.f, 0.f, 0.f);
}

// ---------------- launch ----------------------------------------------------

extern "C" void kernel_launch(void* const* d_in, const int* in_sizes, int n_in,
                              void* d_out, int out_size, void* d_ws, size_t ws_size,
                              hipStream_t stream) {
    (void)in_sizes; (void)n_in; (void)out_size;
    if (ws_size < (size_t)WS_NEEDED) return;   // ws_size constant per process -> same work every call
    const float2* p2      = (const float2*)d_in[0];
    const float4* bbox    = (const float4*)d_in[1];
    const float4* anchors = (const float4*)d_in[2];
    float4* out = (float4*)d_out;

    char* ws = (char*)d_ws;
    u16* h1p     = (u16*)(ws + OFF_H1P);
    u64* fbkeys  = (u64*)(ws + OFF_FBK);       // aliases h1p (dead by fb time)
    u64* cache   = (u64*)(ws + OFF_CACHE);
    u32* hist2   = (u32*)(ws + OFF_HIST2);
    u32* cnt     = (u32*)(ws + OFF_CNT);
    u32* b1g1    = (u32*)(ws + OFF_B1G1);
    u32* selP    = (u32*)(ws + OFF_SELP);
    float4* boxes= (float4*)(ws + OFF_BOX);
    float* areas = (float*)(ws + OFF_AREA);
    u32* maskT   = (u32*)(ws + OFF_MASK);
    u32* flags   = (u32*)(ws + OFF_FLAGS);

    hipMemsetAsync(ws + OFF_HIST2, 0, 131072 + 1024, stream);   // hist2 + cnt

    dim3 g16(H1BLK, BATCH), g64(64, BATCH), gm(TOP1 / 64, BATCH);
    k_hist1     <<<g16,   256, 0, stream>>>(p2, h1p);
    k_select1   <<<BATCH, 256, 0, stream>>>(h1p, b1g1);
    k_hist2cache<<<g64,   256, 0, stream>>>(p2, b1g1, hist2, cnt, cache);
    k_select2   <<<BATCH, 256, 0, stream>>>(hist2, b1g1, selP);
    k_sortdec   <<<BATCH, 1024, 0, stream>>>(cnt, cache, selP, anchors, bbox, boxes, areas);
    k_mask      <<<gm,    256, 0, stream>>>(boxes, areas, maskT);
    k_nms       <<<BATCH, 1024, 0, stream>>>(maskT, boxes, out, flags);
    k_fb        <<<BATCH, 1024, 0, stream>>>(p2, bbox, anchors, b1g1, cnt, flags, fbkeys, out);
}

// Round 6
// 189.064 us; speedup vs baseline: 3.5519x; 1.3153x over previous
//
#include <hip/hip_runtime.h>
#include <math.h>
#include <stdint.h>

typedef uint32_t u32; typedef uint64_t u64; typedef uint16_t u16; typedef int32_t i32;

#define BATCH 8
#define NA    261888      // anchors per batch
#define CHUNK 4092        // elements per hist2cache block (64 blocks/batch)
#define H1CHUNK 16368     // elements per hist1 block (16 blocks/batch)
#define H1BLK 16
#define TOPK  6000        // PRE_NMS_LIMIT (fallback only)
#define PROP  1000        // PROPOSAL_COUNT
#define TOP1  1024        // fast-path window = Jacobi/mask width
#define SORTN 2048        // bitonic size for top-1024 refinement
#define CACHEMAX 8192     // cached candidates >= coarse rank-1024 threshold (~5.1K expected)
#define FBMAX 16384       // fallback candidate capacity (~10.1K expected)
#define MW32  32          // u32 words per 1024-bit candidate bitmap

// ws layout — 2,917,568 B total (< round-5-proven 2,917,632). fbkeys aliases
// h1p (dead by nmsfb time). hist2+cnt are zeroed inline by k_hist1.
#define OFF_H1P   0              // u16 h1p[8][16][4096]  = 1,048,576
#define OFF_FBK   0              // u64 fbkeys[8][16384]  = 1,048,576 (alias, fb only)
#define OFF_CACHE 1048576        // u64 cache[8][8192]    =   524,288
#define OFF_HIST2 1572864        // u32 hist2[8][4096]    =   131,072 (zeroed by k_hist1)
#define OFF_CNT   1703936        // u32 cnt[8*32]         =     1,024 (zeroed by k_hist1)
#define OFF_B1G1  1704960        // u32 [8][4]            =       128
#define OFF_SELP  1705088        // (spare)               =        64
#define OFF_BOX   1705152        // float4 boxes[8][1024] =   131,072
#define OFF_AREA  1836224        // float areas[8][1024]  =    32,768
#define OFF_MASK  1868992        // u32 maskT[8][32][1024]= 1,048,576
#define WS_NEEDED 2917568
#define ZERO_U32S 33024          // (131072 + 1024) / 4

// ---------------- shared exact numerics -------------------------------------

// bit-faithful numpy fp32 decode (no FMA contraction; correctly-rounded exp)
__device__ __forceinline__ void decode_box(const float4 an, const float4 dl,
                                           float4& bx, float& ar) {
    float d0 = __fmul_rn(dl.x, 0.1f), d1 = __fmul_rn(dl.y, 0.1f);
    float d2 = __fmul_rn(dl.z, 0.2f), d3 = __fmul_rn(dl.w, 0.2f);
    float h = __fsub_rn(an.z, an.x), w = __fsub_rn(an.w, an.y);
    float cy = __fadd_rn(__fadd_rn(an.x, __fmul_rn(0.5f, h)), __fmul_rn(d0, h));
    float cx = __fadd_rn(__fadd_rn(an.y, __fmul_rn(0.5f, w)), __fmul_rn(d1, w));
    float h2 = __fmul_rn(h, (float)exp((double)d2));
    float w2 = __fmul_rn(w, (float)exp((double)d3));
    float y1 = __fsub_rn(cy, __fmul_rn(0.5f, h2));
    float x1 = __fsub_rn(cx, __fmul_rn(0.5f, w2));
    float y2 = __fadd_rn(y1, h2);
    float x2 = __fadd_rn(x1, w2);
    y1 = fminf(fmaxf(y1, 0.f), 1.f); x1 = fminf(fmaxf(x1, 0.f), 1.f);
    y2 = fminf(fmaxf(y2, 0.f), 1.f); x2 = fminf(fmaxf(x2, 0.f), 1.f);
    bx = make_float4(y1, x1, y2, x2);
    ar = __fmul_rn(__fsub_rn(y2, y1), __fsub_rn(x2, x1));
}

// suppress(i,j) <=> RN(inter/union) > 0.7f <=> inter >= ((double)0.7f+2^-25)*union
// (product <= 49 significant bits -> double compare EXACT incl. tie-to-even midpoint)
__device__ __forceinline__ bool sup_pred(const float4 bi, const float ai,
                                         const float4 bj, const float aj) {
    const double tmid = (double)0.7f + 0x1p-25;
    float yy1 = fmaxf(bi.x, bj.x), xx1 = fmaxf(bi.y, bj.y);
    float yy2 = fminf(bi.z, bj.z), xx2 = fminf(bi.w, bj.w);
    float ih = fmaxf(__fsub_rn(yy2, yy1), 0.f);
    float iw = fmaxf(__fsub_rn(xx2, xx1), 0.f);
    float inter = __fmul_rn(ih, iw);
    float uni = __fsub_rn(__fadd_rn(ai, aj), inter);
    return (uni > 0.f) && ((double)inter >= tmid * (double)uni);
}

// ---------------- phase 1: exact top-1024 select -----------------------------

// atomic-free partial histograms on bits[31:18]; also zeroes hist2+cnt for the
// downstream pass (replaces hipMemsetAsync dispatch)
__global__ void k_hist1(const float2* __restrict__ p2, u16* __restrict__ h1p,
                        u32* __restrict__ zero_region) {
    __shared__ u32 h[4096];
    const int b = blockIdx.y;
    const int base = blockIdx.x * H1CHUNK;
    int gtid = ((b * H1BLK + blockIdx.x) << 8) | threadIdx.x;   // 0..32767
    for (int z = gtid; z < ZERO_U32S; z += H1BLK * BATCH * 256) zero_region[z] = 0;
    for (int i = threadIdx.x; i < 4096; i += 256) h[i] = 0;
    __syncthreads();
    for (int e = threadIdx.x; e < H1CHUNK; e += 256) {
        u32 bits = __float_as_uint(p2[(size_t)b * NA + base + e].y);
        atomicAdd(&h[bits >> 18], 1u);   // LDS atomic; scores in [0,1)
    }
    __syncthreads();
    u16* dst = h1p + ((size_t)b * H1BLK + blockIdx.x) * 4096;
    for (int i = threadIdx.x; i < 4096; i += 256) dst[i] = (u16)h[i];
}

// merge partials; pick coarse bins for rank-1024 (fast path) and rank-6000 (fb)
__global__ void k_select1(const u16* __restrict__ h1p, u32* __restrict__ b1g1) {
    __shared__ u32 merged[4096];
    __shared__ u32 ps[256];
    const int b = blockIdx.x;
    const u16* src = h1p + (size_t)b * H1BLK * 4096;
    u32 s = 0;
    for (int k = 0; k < 16; ++k) {
        int bin = threadIdx.x * 16 + k;
        u32 m = 0;
        for (int blk = 0; blk < H1BLK; ++blk) m += src[blk * 4096 + bin];
        merged[bin] = m; s += m;
    }
    ps[threadIdx.x] = s;
    __syncthreads();
    if (threadIdx.x == 0) {
        {   // rank TOP1
            u32 acc = 0; int seg = 0;
            for (int t = 255; t >= 0; --t) { if (acc + ps[t] >= TOP1) { seg = t; break; } acc += ps[t]; }
            int b1 = seg * 16; u32 g1 = acc;
            for (int k = 15; k >= 0; --k) {
                u32 c = merged[seg * 16 + k];
                if (g1 + c >= TOP1) { b1 = seg * 16 + k; break; }
                g1 += c;
            }
            b1g1[b * 4] = (u32)b1; b1g1[b * 4 + 1] = g1;
        }
        {   // rank TOPK (fallback threshold only)
            u32 acc = 0; int seg = 0;
            for (int t = 255; t >= 0; --t) { if (acc + ps[t] >= TOPK) { seg = t; break; } acc += ps[t]; }
            int b6 = seg * 16; u32 g6 = acc;
            for (int k = 15; k >= 0; --k) {
                u32 c = merged[seg * 16 + k];
                if (g6 + c >= TOPK) { b6 = seg * 16 + k; break; }
                g6 += c;
            }
            b1g1[b * 4 + 2] = (u32)b6;
        }
    }
}

// fused: refine-histogram bin b1 on bits[17:6] AND cache all candidates with
// bits >= (b1<<18) (~5.1K/batch) via block-aggregated allocation (1 atomic/block)
__global__ void k_hist2cache(const float2* __restrict__ p2, const u32* __restrict__ b1g1,
                             u32* __restrict__ hist2, u32* __restrict__ cnt,
                             u64* __restrict__ cache) {
    __shared__ u32 h[4096];
    __shared__ u32 wtot[4];
    __shared__ u32 wbase;
    const int b = blockIdx.y;
    const u32 b1 = b1g1[b * 4];
    const u32 Pc = b1 << 18;
    const int base = blockIdx.x * CHUNK;
    const int lane = threadIdx.x & 63, wave = threadIdx.x >> 6;
    for (int i = threadIdx.x; i < 4096; i += 256) h[i] = 0;
    __syncthreads();
    u32 vals[16];
    u32 pmask = 0;
    #pragma unroll
    for (int it = 0; it < 16; ++it) {
        int e = it * 256 + threadIdx.x;
        u32 bits = 0;
        if (e < CHUNK) bits = __float_as_uint(p2[(size_t)b * NA + base + e].y);
        vals[it] = bits;
        if (e < CHUNK && bits >= Pc) {
            pmask |= (1u << it);
            if ((bits >> 18) == b1) atomicAdd(&h[(bits >> 6) & 0xFFFu], 1u);
        }
    }
    int c = __popc(pmask);
    int pre = c;                                   // inclusive prefix within wave
    #pragma unroll
    for (int d = 1; d < 64; d <<= 1) {
        int v = __shfl_up(pre, d);
        if (lane >= d) pre += v;
    }
    if (lane == 63) wtot[wave] = (u32)pre;
    __syncthreads();
    if (threadIdx.x == 0) {
        u32 run = 0;
        for (int w = 0; w < 4; ++w) { u32 x = wtot[w]; wtot[w] = run; run += x; }
        wbase = atomicAdd(&cnt[b * 32], run);      // padded counter: no line sharing
    }
    __syncthreads();
    u32 pos = wbase + wtot[wave] + (u32)(pre - c);
    #pragma unroll
    for (int it = 0; it < 16; ++it) {
        if ((pmask >> it) & 1u) {
            if (pos < CACHEMAX) {
                u32 a = (u32)(base + it * 256 + threadIdx.x);
                cache[(size_t)b * CACHEMAX + pos] = ((u64)(~vals[it]) << 32) | (u64)a;
            }
            ++pos;
        }
    }
    for (int i = threadIdx.x; i < 4096; i += 256)
        if (h[i]) atomicAdd(&hist2[b * 4096 + i], h[i]);
}

// fused select2 + filter + bitonic sort 2048 (exact lax.top_k order:
// key = (~score_bits, index)) + decode of the sorted top-1024
__global__ __launch_bounds__(1024) void k_sortdec(const u32* __restrict__ hist2,
                                                  const u32* __restrict__ b1g1,
                                                  const u32* __restrict__ cnt,
                                                  const u64* __restrict__ cache,
                                                  const float4* __restrict__ anchors,
                                                  const float4* __restrict__ bbox,
                                                  float4* __restrict__ boxes,
                                                  float* __restrict__ areas) {
    __shared__ u64 s[SORTN];
    __shared__ u32 ps[256];
    __shared__ u32 m;
    __shared__ u32 selP_sh;
    const int b = blockIdx.x;
    const u32 b1 = b1g1[b * 4], g1 = b1g1[b * 4 + 1];
    // ---- inline select2: refine threshold to rank-1024 on bits[17:6] ----
    if (threadIdx.x < 256) {
        const u32* h = hist2 + b * 4096;
        u32 sum = 0;
        for (int k = 0; k < 16; ++k) sum += h[threadIdx.x * 16 + k];
        ps[threadIdx.x] = sum;
    }
    if (threadIdx.x == 0) m = 0;
    for (int i = threadIdx.x; i < SORTN; i += 1024) s[i] = ~0ull;
    __syncthreads();
    if (threadIdx.x == 0) {
        const u32* h = hist2 + b * 4096;
        u32 acc = g1; int seg = 0;
        for (int t = 255; t >= 0; --t) {
            if (acc + ps[t] >= TOP1) { seg = t; break; }
            acc += ps[t];
        }
        int b2 = seg * 16; u32 g = acc;
        for (int k = 15; k >= 0; --k) {
            u32 c = h[seg * 16 + k];
            if (g + c >= TOP1) { b2 = seg * 16 + k; break; }
            g += c;
        }
        selP_sh = (b1 << 18) | ((u32)b2 << 6);   // count(bits>=P) in [1024, ~1030]
    }
    __syncthreads();
    const u32 P = selP_sh;
    const u64 thrKey = ((u64)(~P) << 32) | 0xFFFFFFFFull;   // key<=thrKey <=> bits>=P
    u32 nc = cnt[b * 32]; if (nc > CACHEMAX) nc = CACHEMAX;
    for (int t = threadIdx.x; t < (int)nc; t += 1024) {
        u64 key = cache[(size_t)b * CACHEMAX + t];
        if (key <= thrKey) {
            u32 slot = atomicAdd(&m, 1u);
            if (slot < SORTN) s[slot] = key;     // overflow impossible; fb guards anyway
        }
    }
    __syncthreads();
    for (int k = 2; k <= SORTN; k <<= 1) {
        for (int j = k >> 1; j > 0; j >>= 1) {
            int p = threadIdx.x;                 // exactly SORTN/2 pairs
            int i = ((p & ~(j - 1)) << 1) | (p & (j - 1));
            int l = i | j;
            u64 a = s[i], c = s[l];
            bool up = ((i & k) == 0);
            if ((a > c) == up) { s[i] = c; s[l] = a; }
            __syncthreads();
        }
    }
    int i = threadIdx.x;                          // 0..1023: decode sorted top-1024
    u32 idx = (u32)s[i];
    float4 bx; float ar;
    if (idx == 0xFFFFFFFFu) {                     // unreachable (n1>=1024); OOB guard
        bx = make_float4(-5.f, -5.f, -5.f, -5.f); ar = 0.f;
    } else {
        decode_box(anchors[(size_t)b * NA + idx], bbox[(size_t)b * NA + idx], bx, ar);
    }
    boxes[b * TOP1 + i] = bx;
    areas[b * TOP1 + i] = ar;
}

// ---------------- phase 3: NMS ----------------------------------------------

// one wave per mask row; bi in registers, bj coalesced from global (L1-resident
// 16 KB/batch); no LDS, no __syncthreads, 16 independent chunks for ILP.
// maskT[b][w][i] = word w (candidates 32w..32w+31) of row i (TRANSPOSED)
__global__ __launch_bounds__(256) void k_mask(const float4* __restrict__ boxes,
                                              const float* __restrict__ areas,
                                              u32* __restrict__ mt_all) {
    const int b = blockIdx.y;
    const int wave = threadIdx.x >> 6, lane = threadIdx.x & 63;
    const int i = blockIdx.x * 4 + wave;          // row 0..1023 (grid.x = 256)
    u32* mt = mt_all + (size_t)b * MW32 * TOP1;
    float4 bi = boxes[b * TOP1 + i];
    float  ai = areas[b * TOP1 + i];
    #pragma unroll
    for (int c = 0; c < 16; ++c) {
        float4 bj = boxes[b * TOP1 + c * 64 + lane];
        float  aj = areas[b * TOP1 + c * 64 + lane];
        u64 word = __ballot(sup_pred(bi, ai, bj, aj));
        if (lane == 0) {
            mt[(2 * c) * TOP1 + i]     = (u32)word;
            mt[(2 * c + 1) * TOP1 + i] = (u32)(word >> 32);
        }
    }
}

// Jacobi fixed-point NMS (unique fixed point == greedy result) + inline exact
// fallback (expected never taken; redoes full reference computation if Jacobi
// didn't converge, accepts < PROP within the 1024 window, or cache overflowed)
__global__ __launch_bounds__(1024) void k_nmsfb(const u32* __restrict__ mt_all,
                                                const float4* __restrict__ boxes,
                                                const float2* __restrict__ p2,
                                                const float4* __restrict__ bbox,
                                                const float4* __restrict__ anchors,
                                                const u32* __restrict__ b1g1,
                                                const u32* __restrict__ cnt,
                                                u64* __restrict__ fbkeys,
                                                float4* __restrict__ out) {
    __shared__ u32 valid[MW32];
    __shared__ u32 wpre[MW32 + 1];
    __shared__ u32 chg;
    __shared__ float4 abox[PROP];
    __shared__ float  aar[PROP];
    __shared__ u32 nsh;
    const int b = blockIdx.x;
    const int i = threadIdx.x;                 // candidate 0..1023
    const int wv = i >> 6, lane = i & 63;
    const int wi = i >> 5;
    const u32* mt = mt_all + (size_t)b * MW32 * TOP1;
    u32 row[MW32];                             // row i, masked to j<i (coalesced loads)
    #pragma unroll
    for (int w = 0; w < MW32; ++w) row[w] = 0;
    for (int w = 0; w < wi; ++w) row[w] = mt[w * TOP1 + i];
    row[wi] = mt[wi * TOP1 + i] & ((1u << (i & 31)) - 1u);
    if (i < MW32) valid[i] = 0xFFFFFFFFu;
    bool conv = false;
    for (int it = 0; it < 48; ++it) {
        __syncthreads();
        if (i == 0) chg = 0;
        u32 sup = 0;
        #pragma unroll
        for (int w = 0; w < MW32; ++w) sup |= valid[w] & row[w];
        u64 nb = __ballot(sup == 0u);
        __syncthreads();
        if (lane == 0) {
            u32 lo = (u32)nb, hi = (u32)(nb >> 32);
            if (valid[2 * wv] != lo)     { valid[2 * wv] = lo;     atomicOr(&chg, 1u); }
            if (valid[2 * wv + 1] != hi) { valid[2 * wv + 1] = hi; atomicOr(&chg, 1u); }
        }
        __syncthreads();
        if (chg == 0u) { conv = true; break; }
    }
    __syncthreads();
    if (i == 0) {
        u32 r = 0;
        for (int w = 0; w < MW32; ++w) { wpre[w] = r; r += __popc(valid[w]); }
        wpre[MW32] = r;
    }
    __syncthreads();
    u32 V = wpre[MW32];
    if (conv && V >= PROP && cnt[b * 32] <= CACHEMAX) {   // fast path (expected always)
        u32 vw = valid[wi];
        bool isv = ((vw >> (i & 31)) & 1u) != 0;
        u32 rank = wpre[wi] + __popc(vw & ((1u << (i & 31)) - 1u));
        if (isv && rank < PROP) out[b * PROP + rank] = boxes[b * TOP1 + i];
        return;                                           // V>=PROP: no tail zeros needed
    }
    // ---- exact fallback: redo reference computation from raw inputs ----
    if (i == 0) nsh = 0;
    __syncthreads();
    u32 P6 = b1g1[b * 4 + 2] << 18;            // coarse rank-6000 threshold
    for (int a = i; a < NA; a += 1024) {
        u32 bits = __float_as_uint(p2[(size_t)b * NA + a].y);
        if (bits >= P6) {
            u32 p = atomicAdd(&nsh, 1u);
            if (p < FBMAX) fbkeys[(size_t)b * FBMAX + p] = ((u64)(~bits) << 32) | (u64)a;
        }
    }
    __syncthreads();
    u32 n = nsh; if (n > FBMAX) n = FBMAX;     // ~10.1K expected; overflow impossible
    volatile u64* vk = (volatile u64*)(fbkeys + (size_t)b * FBMAX);
    for (int i2 = (int)n + i; i2 < FBMAX; i2 += 1024) vk[i2] = ~0ull;
    __syncthreads();
    for (int k = 2; k <= FBMAX; k <<= 1) {     // global-memory bitonic, exact order
        for (int j = k >> 1; j > 0; j >>= 1) {
            for (int p = i; p < FBMAX / 2; p += 1024) {
                int ii = ((p & ~(j - 1)) << 1) | (p & (j - 1));
                int l = ii | j;
                u64 a = vk[ii], c = vk[l];
                bool up = ((ii & k) == 0);
                if ((a > c) == up) { vk[ii] = c; vk[l] = a; }
            }
            __syncthreads();
        }
    }
    int acc_n = 0;
    int limit = (int)n < TOPK ? (int)n : TOPK;
    for (int t = 0; t < limit && acc_n < PROP; ++t) {
        u32 idx = (u32)vk[t];
        float4 bi2; float ai2;
        decode_box(anchors[(size_t)b * NA + idx], bbox[(size_t)b * NA + idx], bi2, ai2);
        int pred = 0;
        if (i < acc_n) pred = sup_pred(bi2, ai2, abox[i], aar[i]) ? 1 : 0;
        int any = __syncthreads_or(pred);
        if (!any) {
            if (i == 0) {
                abox[acc_n] = bi2; aar[acc_n] = ai2;
                out[b * PROP + acc_n] = bi2;
            }
            ++acc_n;
            __syncthreads();
        }
    }
    for (int t = acc_n + i; t < PROP; t += 1024)
        out[b * PROP + t] = make_float4(0.f, 0.f, 0.f, 0.f);
}

// ---------------- launch ----------------------------------------------------

extern "C" void kernel_launch(void* const* d_in, const int* in_sizes, int n_in,
                              void* d_out, int out_size, void* d_ws, size_t ws_size,
                              hipStream_t stream) {
    (void)in_sizes; (void)n_in; (void)out_size;
    if (ws_size < (size_t)WS_NEEDED) return;   // ws_size constant per process -> same work every call
    const float2* p2      = (const float2*)d_in[0];
    const float4* bbox    = (const float4*)d_in[1];
    const float4* anchors = (const float4*)d_in[2];
    float4* out = (float4*)d_out;

    char* ws = (char*)d_ws;
    u16* h1p     = (u16*)(ws + OFF_H1P);
    u64* fbkeys  = (u64*)(ws + OFF_FBK);       // aliases h1p (dead by nmsfb time)
    u64* cache   = (u64*)(ws + OFF_CACHE);
    u32* hist2   = (u32*)(ws + OFF_HIST2);
    u32* cnt     = (u32*)(ws + OFF_CNT);
    u32* b1g1    = (u32*)(ws + OFF_B1G1);
    float4* boxes= (float4*)(ws + OFF_BOX);
    float* areas = (float*)(ws + OFF_AREA);
    u32* maskT   = (u32*)(ws + OFF_MASK);

    dim3 g16(H1BLK, BATCH), g64(64, BATCH), gmask(TOP1 / 4, BATCH);
    k_hist1     <<<g16,   256, 0, stream>>>(p2, h1p, (u32*)(ws + OFF_HIST2));
    k_select1   <<<BATCH, 256, 0, stream>>>(h1p, b1g1);
    k_hist2cache<<<g64,   256, 0, stream>>>(p2, b1g1, hist2, cnt, cache);
    k_sortdec   <<<BATCH, 1024, 0, stream>>>(hist2, b1g1, cnt, cache, anchors, bbox, boxes, areas);
    k_mask      <<<gmask, 256, 0, stream>>>(boxes, areas, maskT);
    k_nmsfb     <<<BATCH, 1024, 0, stream>>>(maskT, boxes, p2, bbox, anchors, b1g1, cnt, fbkeys, out);
}